// Round 9
// baseline (1491.693 us; speedup 1.0000x reference)
//
#include <hip/hip_runtime.h>
#include <hip/hip_bf16.h>

// Problem constants (from reference)
#define NN 50000
#define NE 800000
#define HD 128
#define NB 391              // buckets of 128 dst nodes: (NN+127)>>7

typedef unsigned short u16;
typedef unsigned char u8;
typedef unsigned int u32;
typedef __attribute__((ext_vector_type(8))) short short8;
typedef __attribute__((ext_vector_type(4))) float floatx4;
typedef __attribute__((ext_vector_type(2))) float f32x2;
#define MFMA __builtin_amdgcn_mfma_f32_16x16x32_bf16

__device__ __forceinline__ float bf2f(u16 v) {
    union { unsigned int u; float f; } x; x.u = ((unsigned int)v) << 16; return x.f;
}
__device__ __forceinline__ u16 f2bf(float f) {
    union { unsigned int u; float f; } x; x.f = f;
    unsigned int r = x.u + 0x7fff + ((x.u >> 16) & 1);
    return (u16)(r >> 16);
}
// fast ELU: t>0 ? t : exp2(t*log2e)-1  (v_exp_f32 path, ~4 instrs)
__device__ __forceinline__ float elu_fast(float t) {
    return t > 0.f ? t : (__builtin_amdgcn_exp2f(t * 1.44269504088896f) - 1.f);
}
// pack 2 f32 -> 2 fp8 (e4m3) in low 16 bits
__device__ __forceinline__ u32 pk_fp8(float a, float b) {
    return __builtin_amdgcn_cvt_pk_fp8_f32(a, b, 0u, false);
}

// convert 8 consecutive f32 to a bf16 A-fragment
__device__ __forceinline__ short8 cvt8(const float* p) {
    const float4* q = (const float4*)p;
    float4 a = q[0], b = q[1];
    short8 r;
    r[0] = (short)f2bf(a.x); r[1] = (short)f2bf(a.y); r[2] = (short)f2bf(a.z); r[3] = (short)f2bf(a.w);
    r[4] = (short)f2bf(b.x); r[5] = (short)f2bf(b.y); r[6] = (short)f2bf(b.z); r[7] = (short)f2bf(b.w);
    return r;
}

// K0: weight prep -> bf16 transposed layouts [c][k]; zeroes bucket counters
__global__ void k_wb(const float* __restrict__ we0, const float* __restrict__ we1,
                     const float* __restrict__ wn0, const float* __restrict__ wn1,
                     u16* __restrict__ wcombt, u16* __restrict__ we1t,
                     u16* __restrict__ wn0t, u16* __restrict__ wn1t,
                     int* __restrict__ gbc) {
    int i = blockIdx.x * 256 + threadIdx.x;
    if (i < 32768) {                       // wcombt
        int c = i >> 7, k = i & 127;
        float v;
        if (c < 128) v = we0[k * 128 + c] + we0[(256 + k) * 128 + c];
        else { int cc = c - 128; v = we0[(128 + k) * 128 + cc] - we0[(256 + k) * 128 + cc]; }
        wcombt[i] = f2bf(v);
    } else if (i < 49152) {                // we1t
        int j = i - 32768; int c = j >> 7, k = j & 127;
        we1t[j] = f2bf(we1[k * 128 + c]);
    } else if (i < 81920) {                // wn0t (k = 0..255)
        int j = i - 49152; int c = j >> 8, k = j & 255;
        wn0t[j] = f2bf(wn0[k * 128 + c]);
    } else if (i < 98304) {                // wn1t
        int j = i - 81920; int c = j >> 7, k = j & 127;
        wn1t[j] = f2bf(wn1[k * 128 + c]);
    } else if (i < 98304 + NB + 1) {       // gbc = 0
        gbc[i - 98304] = 0;
    }
}

// K2: MFMA [P|Q] = x @ Wcomb. 32 rows/block, 4 waves = (2 row-tiles x 2 col-halves).
// p8 (fp8 quads): p8[n][4i+0,1] = P[2i],P[2i+1] ; p8[n][4i+2,3] = x[2i],x[2i+1]
// qb[n][128] = Q (bf16) ; xb[n][128] = x (bf16)
__global__ __launch_bounds__(256) void k_pq_mfma(const float* __restrict__ x,
                                                 const u16* __restrict__ wcombt,
                                                 u8* __restrict__ p8, u16* __restrict__ qb,
                                                 u16* __restrict__ xb) {
    __shared__ u8  pq[32 * 272];
    __shared__ u16 qt[32 * 136];
    int r0 = blockIdx.x * 32;
    int tid = threadIdx.x, wid = tid >> 6, lane = tid & 63;
    int arow = lane & 15, kblk = lane >> 4;
    int rw = (wid & 1) * 16;
    int ch = (wid >> 1) * 128;
    for (int s = tid; s < 32 * 64; s += 256) {
        int r = s >> 6, i = s & 63;
        int n = r0 + r;
        float2 v = (n < NN) ? *(const float2*)&x[(size_t)n * 128 + 2 * i] : make_float2(0.f, 0.f);
        *(u16*)&pq[r * 272 + 4 * i + 2] = (u16)pk_fp8(v.x, v.y);
        if (n < NN) {
            ushort2 o = { f2bf(v.x), f2bf(v.y) };
            *(ushort2*)&xb[(size_t)n * 128 + 2 * i] = o;
        }
    }
    floatx4 acc[8];
#pragma unroll
    for (int n0 = 0; n0 < 8; n0++) acc[n0] = (floatx4)(0.f);
    int nrow = r0 + rw + arow; if (nrow >= NN) nrow = NN - 1;
#pragma unroll
    for (int ks = 0; ks < 4; ks++) {
        short8 a = cvt8(&x[(size_t)nrow * 128 + ks * 32 + kblk * 8]);
#pragma unroll
        for (int n0 = 0; n0 < 8; n0++) {
            short8 b = *(const short8*)&wcombt[(size_t)(ch + n0 * 16 + arow) * 128 + ks * 32 + kblk * 8];
            acc[n0] = MFMA(a, b, acc[n0], 0, 0, 0);
        }
    }
#pragma unroll
    for (int n0 = 0; n0 < 8; n0++) {
#pragma unroll
        for (int j = 0; j < 4; j++) {
            int r = rw + kblk * 4 + j;
            int col = ch + n0 * 16 + arow;
            if (ch == 0) {
                u32 pk = pk_fp8(acc[n0][j], acc[n0][j]);
                pq[r * 272 + 4 * (col >> 1) + (col & 1)] = (u8)pk;
            } else {
                qt[r * 136 + (col - 128)] = f2bf(acc[n0][j]);
            }
        }
    }
    __syncthreads();
    for (int s = tid; s < 32 * 16; s += 256) {
        int r = s >> 4, cb = (s & 15) * 16;
        int n = r0 + r;
        if (n < NN) *(short8*)&p8[(size_t)n * 256 + cb] = *(const short8*)&pq[r * 272 + cb];
    }
    for (int s = tid; s < 32 * 16; s += 256) {
        int r = s >> 4, cb = (s & 15) * 8;
        int n = r0 + r;
        if (n < NN) *(short8*)&qb[(size_t)n * 128 + cb] = *(const short8*)&qt[r * 136 + cb];
    }
}

// K3: bucket histogram (LDS-first). 16 edges/thread, 4096/block.
__global__ __launch_bounds__(256) void k_bhist(const int* __restrict__ ei, int* __restrict__ gbc) {
    __shared__ int bh[NB];
    int tid = threadIdx.x;
    int bs = blockIdx.x * 4096;
    for (int t = tid; t < NB; t += 256) bh[t] = 0;
    __syncthreads();
#pragma unroll
    for (int k = 0; k < 4; k++) {
        int e = bs + k * 1024 + tid * 4;
        if (e < NE) {
            int4 d = *(const int4*)&ei[NE + e];
            atomicAdd(&bh[d.x >> 7], 1); atomicAdd(&bh[d.y >> 7], 1);
            atomicAdd(&bh[d.z >> 7], 1); atomicAdd(&bh[d.w >> 7], 1);
        }
    }
    __syncthreads();
    for (int t = tid; t < NB; t += 256)
        if (bh[t]) atomicAdd(&gbc[t], bh[t]);
}

// K4: scan bucket counts -> boffs[NB+1], gcursor[b] = boffs[b]. One block.
__global__ __launch_bounds__(512) void k_bscan(const int* __restrict__ gbc,
                                               int* __restrict__ boffs, int* __restrict__ gcursor) {
    __shared__ int s[512];
    int t = threadIdx.x;
    int v = (t < NB) ? gbc[t] : 0;
    s[t] = v; __syncthreads();
    for (int off = 1; off < 512; off <<= 1) {
        int tv = (t >= off) ? s[t - off] : 0;
        __syncthreads();
        s[t] += tv; __syncthreads();
    }
    if (t < NB) {
        boffs[t + 1] = s[t];
        gcursor[t] = s[t] - v;
        if (t == 0) boffs[0] = 0;
    }
}

// K5: bucket scatter. 8192 edges/block, 32/thread.
// phases: LDS hist -> reserve global runs -> write packed u32 (src | dl<<16).
__global__ __launch_bounds__(256) void k_bscat(const int* __restrict__ ei,
                                               int* __restrict__ gcursor, u32* __restrict__ ebuf) {
    __shared__ int lh[NB], lbase[NB], lrank[NB];
    int tid = threadIdx.x;
    int bs = blockIdx.x * 8192;
    for (int t = tid; t < NB; t += 256) { lh[t] = 0; lrank[t] = 0; }
    __syncthreads();
    int srcv[32], dstv[32];
#pragma unroll
    for (int k = 0; k < 8; k++) {
        int e = bs + k * 1024 + tid * 4;
        int4 s4, d4;
        if (e < NE) { s4 = *(const int4*)&ei[e]; d4 = *(const int4*)&ei[NE + e]; }
        else { s4 = make_int4(0, 0, 0, 0); d4 = make_int4(-1, -1, -1, -1); }
        srcv[4 * k + 0] = s4.x; srcv[4 * k + 1] = s4.y; srcv[4 * k + 2] = s4.z; srcv[4 * k + 3] = s4.w;
        dstv[4 * k + 0] = d4.x; dstv[4 * k + 1] = d4.y; dstv[4 * k + 2] = d4.z; dstv[4 * k + 3] = d4.w;
    }
#pragma unroll
    for (int i = 0; i < 32; i++)
        if (dstv[i] >= 0) atomicAdd(&lh[dstv[i] >> 7], 1);
    __syncthreads();
    for (int t = tid; t < NB; t += 256)
        if (lh[t]) lbase[t] = atomicAdd(&gcursor[t], lh[t]);
    __syncthreads();
#pragma unroll
    for (int i = 0; i < 32; i++) {
        int d = dstv[i];
        if (d >= 0) {
            int b = d >> 7;
            int r = atomicAdd(&lrank[b], 1);
            ebuf[lbase[b] + r] = (u32)srcv[i] | ((u32)(d & 127) << 16);
        }
    }
}

// K6 v5: LDS-accumulate aggregation. One block (512 thr, 8 waves) per 128-node bucket.
// Per edge (wave-wide): gather fp8 quad row of src (4 B/lane) + Q[dst] pair (L1-hot),
// elu, ds_add_f32 into acc[dl]. Degree counted in LDS. Epilogue normalizes + writes esumx.
__global__ __launch_bounds__(512) void k_agg(const u8* __restrict__ p8, const u16* __restrict__ qb,
                                             const u16* __restrict__ xb,
                                             const int* __restrict__ boffs, const u32* __restrict__ ebuf,
                                             u16* __restrict__ esumx) {
    __shared__ float acc[128 * 256];   // 128 KB
    __shared__ int ndeg[128];
    const u32* p8r = (const u32*)p8;
    int bb = blockIdx.x;
    int tid = threadIdx.x, wave = tid >> 6, lane = tid & 63;
    int nodebase = bb * 128;
    for (int t = tid; t < 128 * 64; t += 512) ((float4*)acc)[t] = make_float4(0.f, 0.f, 0.f, 0.f);
    for (int t = tid; t < 128; t += 512) ndeg[t] = 0;
    __syncthreads();
    int beg = boffs[bb], end = boffs[bb + 1];
    for (int s = beg + wave * 8; s < end; s += 64) {
        int m = end - s; if (m > 8) m = 8;
        u32 pe[8];
#pragma unroll
        for (int j = 0; j < 8; j++) pe[j] = ebuf[s + (j < m ? j : m - 1)];
        u32 d[8]; ushort2 q2[8];
#pragma unroll
        for (int j = 0; j < 8; j++) {
            int src = pe[j] & 0xFFFF;
            int dl = (pe[j] >> 16) & 127;
            d[j] = p8r[(size_t)src * 64 + lane];
            q2[j] = *(const ushort2*)(qb + (size_t)(nodebase + dl) * 128 + 2 * lane);
        }
#pragma unroll
        for (int j = 0; j < 8; j++) {
            if (j < m) {
                int dl = (pe[j] >> 16) & 127;
                f32x2 pp = __builtin_amdgcn_cvt_pk_f32_fp8(d[j], false);
                f32x2 xp = __builtin_amdgcn_cvt_pk_f32_fp8(d[j], true);
                float e0 = elu_fast(pp[0] + bf2f(q2[j].x));
                float e1 = elu_fast(pp[1] + bf2f(q2[j].y));
                int base = dl * 256 + 2 * lane;
                atomicAdd(&acc[base], e0);
                atomicAdd(&acc[base + 1], e1);
                atomicAdd(&acc[base + 128], xp[0]);
                atomicAdd(&acc[base + 129], xp[1]);
                if (lane == 0) atomicAdd(&ndeg[dl], 1);
            }
        }
    }
    __syncthreads();
    // epilogue: esumx[n][0:128] = esum/max(c,1); [128:256] = (xsum - c*x[n])/max(c,1)
    for (int t = tid; t < 128 * 32; t += 512) {
        int dl = t >> 5, cb = (t & 31) * 4;
        int n = nodebase + dl;
        if (n >= NN) continue;
        float cntf = (float)ndeg[dl];
        float inv = 1.f / fmaxf(cntf, 1.f);
        float4 ev = *(const float4*)&acc[dl * 256 + cb];
        float4 xv = *(const float4*)&acc[dl * 256 + 128 + cb];
        ushort4 xo = *(const ushort4*)&xb[(size_t)n * 128 + cb];
        ushort4 oe = { f2bf(ev.x * inv), f2bf(ev.y * inv), f2bf(ev.z * inv), f2bf(ev.w * inv) };
        ushort4 os = { f2bf((xv.x - cntf * bf2f(xo.x)) * inv),
                       f2bf((xv.y - cntf * bf2f(xo.y)) * inv),
                       f2bf((xv.z - cntf * bf2f(xo.z)) * inv),
                       f2bf((xv.w - cntf * bf2f(xo.w)) * inv) };
        *(ushort4*)&esumx[(size_t)n * 256 + cb] = oe;
        *(ushort4*)&esumx[(size_t)n * 256 + 128 + cb] = os;
    }
}

// K7: MFMA node MLP. 128 rows/block, 4 waves; wave owns rows end-to-end, no barriers,
// all global inputs prefetched at entry.
__global__ __launch_bounds__(256, 2) void k_node_mfma(const float* __restrict__ x,
                                                      const u16* __restrict__ xb,
                                                      const u16* __restrict__ esumx,
                                                      const u16* __restrict__ we1t,
                                                      const u16* __restrict__ wn0t,
                                                      const u16* __restrict__ wn1t,
                                                      float* __restrict__ out) {
    __shared__ u16 tile[128 * 136];
    int r0 = blockIdx.x * 128;
    int tid = threadIdx.x, wid = tid >> 6, lane = tid & 63;
    int arow = lane & 15, kblk = lane >> 4;
    int rbase = wid * 32;
    int nrow[2];
#pragma unroll
    for (int rt = 0; rt < 2; rt++) {
        int n = r0 + rbase + rt * 16 + arow; if (n >= NN) n = NN - 1;
        nrow[rt] = n;
    }
    short8 stg[8];
#pragma unroll
    for (int t = 0; t < 8; t++) {
        int idx = t * 64 + lane;
        int r = idx >> 4, cb = (idx & 15) * 8;
        int n = r0 + rbase + r; if (n >= NN) n = NN - 1;
        stg[t] = *(const short8*)&esumx[(size_t)n * 256 + 128 + cb];
    }
    short8 a1[2][4], ax[2][4];
#pragma unroll
    for (int rt = 0; rt < 2; rt++)
#pragma unroll
        for (int ks = 0; ks < 4; ks++) {
            a1[rt][ks] = *(const short8*)&esumx[(size_t)nrow[rt] * 256 + ks * 32 + kblk * 8];
            ax[rt][ks] = *(const short8*)&xb[(size_t)nrow[rt] * 128 + ks * 32 + kblk * 8];
        }
#pragma unroll
    for (int t = 0; t < 8; t++) {
        int idx = t * 64 + lane;
        int r = rbase + (idx >> 4), cb = (idx & 15) * 8;
        *(short8*)&tile[r * 136 + cb] = stg[t];
    }
    floatx4 acc[2][8];
#pragma unroll
    for (int rt = 0; rt < 2; rt++)
#pragma unroll
        for (int n0 = 0; n0 < 8; n0++) acc[rt][n0] = (floatx4)(0.f);
#pragma unroll
    for (int ks = 0; ks < 4; ks++)
#pragma unroll
        for (int n0 = 0; n0 < 8; n0++) {
            short8 b = *(const short8*)&we1t[(size_t)(n0 * 16 + arow) * 128 + ks * 32 + kblk * 8];
            acc[0][n0] = MFMA(a1[0][ks], b, acc[0][n0], 0, 0, 0);
            acc[1][n0] = MFMA(a1[1][ks], b, acc[1][n0], 0, 0, 0);
        }
#pragma unroll
    for (int rt = 0; rt < 2; rt++)
#pragma unroll
        for (int n0 = 0; n0 < 8; n0++)
#pragma unroll
            for (int j = 0; j < 4; j++) {
                int rloc = rbase + rt * 16 + kblk * 4 + j;
                int col = n0 * 16 + arow;
                float m = acc[rt][n0][j] + bf2f(tile[rloc * 136 + col]);
                tile[rloc * 136 + col] = f2bf(m);
            }
#pragma unroll
    for (int rt = 0; rt < 2; rt++)
#pragma unroll
        for (int n0 = 0; n0 < 8; n0++) acc[rt][n0] = (floatx4)(0.f);
#pragma unroll
    for (int ks = 0; ks < 4; ks++) {
        short8 am[2];
#pragma unroll
        for (int rt = 0; rt < 2; rt++)
            am[rt] = *(const short8*)&tile[(rbase + rt * 16 + arow) * 136 + ks * 32 + kblk * 8];
#pragma unroll
        for (int n0 = 0; n0 < 8; n0++) {
            short8 bx = *(const short8*)&wn0t[(size_t)(n0 * 16 + arow) * 256 + ks * 32 + kblk * 8];
            short8 bm = *(const short8*)&wn0t[(size_t)(n0 * 16 + arow) * 256 + 128 + ks * 32 + kblk * 8];
#pragma unroll
            for (int rt = 0; rt < 2; rt++) {
                acc[rt][n0] = MFMA(ax[rt][ks], bx, acc[rt][n0], 0, 0, 0);
                acc[rt][n0] = MFMA(am[rt], bm, acc[rt][n0], 0, 0, 0);
            }
        }
    }
#pragma unroll
    for (int rt = 0; rt < 2; rt++)
#pragma unroll
        for (int n0 = 0; n0 < 8; n0++)
#pragma unroll
            for (int j = 0; j < 4; j++) {
                int rloc = rbase + rt * 16 + kblk * 4 + j;
                tile[rloc * 136 + n0 * 16 + arow] = f2bf(elu_fast(acc[rt][n0][j]));
            }
#pragma unroll
    for (int rt = 0; rt < 2; rt++)
#pragma unroll
        for (int n0 = 0; n0 < 8; n0++) acc[rt][n0] = (floatx4)(0.f);
#pragma unroll
    for (int ks = 0; ks < 4; ks++) {
        short8 a[2];
#pragma unroll
        for (int rt = 0; rt < 2; rt++)
            a[rt] = *(const short8*)&tile[(rbase + rt * 16 + arow) * 136 + ks * 32 + kblk * 8];
#pragma unroll
        for (int n0 = 0; n0 < 8; n0++) {
            short8 b = *(const short8*)&wn1t[(size_t)(n0 * 16 + arow) * 128 + ks * 32 + kblk * 8];
            acc[0][n0] = MFMA(a[0], b, acc[0][n0], 0, 0, 0);
            acc[1][n0] = MFMA(a[1], b, acc[1][n0], 0, 0, 0);
        }
    }
#pragma unroll
    for (int rt = 0; rt < 2; rt++)
#pragma unroll
        for (int n0 = 0; n0 < 8; n0++)
#pragma unroll
            for (int j = 0; j < 4; j++)
                tile[(rbase + rt * 16 + kblk * 4 + j) * 136 + n0 * 16 + arow] = f2bf(acc[rt][n0][j]);
#pragma unroll
    for (int t = 0; t < 16; t++) {
        int idx = t * 64 + lane;
        int r = idx >> 5, cb = (idx & 31) * 4;
        int n = r0 + rbase + r;
        if (n < NN) {
            float4 xv = *(const float4*)&x[(size_t)n * 128 + cb];
            ushort4 tv = *(const ushort4*)&tile[(rbase + r) * 136 + cb];
            float4 o = { xv.x + bf2f(tv.x), xv.y + bf2f(tv.y), xv.z + bf2f(tv.z), xv.w + bf2f(tv.w) };
            *(float4*)&out[(size_t)n * 128 + cb] = o;
        }
    }
}

extern "C" void kernel_launch(void* const* d_in, const int* in_sizes, int n_in,
                              void* d_out, int out_size, void* d_ws, size_t ws_size,
                              hipStream_t stream) {
    const float* x       = (const float*)d_in[0];
    const int* ei        = (const int*)d_in[1];   // int64 in reference -> int32 from harness
    const float* we0     = (const float*)d_in[2];
    const float* we1     = (const float*)d_in[3];
    const float* wn0     = (const float*)d_in[4];
    const float* wn1     = (const float*)d_in[5];
    float* out           = (float*)d_out;

    char* w = (char*)d_ws;
    size_t off = 0;
    auto alloc = [&](size_t bytes) -> void* {
        off = (off + 255) & ~(size_t)255;
        void* p = w + off;
        off += bytes;
        return p;
    };
    u16*   wcombt = (u16*)alloc(256 * 128 * sizeof(u16));
    u16*   we1t   = (u16*)alloc(128 * 128 * sizeof(u16));
    u16*   wn0t   = (u16*)alloc(128 * 256 * sizeof(u16));
    u16*   wn1t   = (u16*)alloc(128 * 128 * sizeof(u16));
    u8*    p8     = (u8*)alloc((size_t)NN * 256 * sizeof(u8));
    u16*   qb     = (u16*)alloc((size_t)NN * 128 * sizeof(u16));
    u16*   xb     = (u16*)alloc((size_t)NN * 128 * sizeof(u16));
    u16*   esumx  = (u16*)alloc((size_t)NN * 256 * sizeof(u16));
    int*   gbc    = (int*)alloc((NB + 1) * sizeof(int));
    int*   boffs  = (int*)alloc((NB + 1) * sizeof(int));
    int*   gcursor= (int*)alloc((NB + 1) * sizeof(int));
    u32*   ebuf   = (u32*)alloc((size_t)NE * sizeof(u32));
    (void)ws_size; (void)in_sizes; (void)n_in; (void)out_size;  // ~65 MB of d_ws used

    k_wb<<<(98304 + NB + 1 + 255) / 256, 256, 0, stream>>>(we0, we1, wn0, wn1,
                                                           wcombt, we1t, wn0t, wn1t, gbc);
    k_pq_mfma<<<(NN + 31) / 32, 256, 0, stream>>>(x, wcombt, p8, qb, xb);
    k_bhist<<<(NE + 4095) / 4096, 256, 0, stream>>>(ei, gbc);
    k_bscan<<<1, 512, 0, stream>>>(gbc, boffs, gcursor);
    k_bscat<<<(NE + 8191) / 8192, 256, 0, stream>>>(ei, gcursor, ebuf);
    k_agg<<<NB, 512, 0, stream>>>(p8, qb, xb, boffs, ebuf, esumx);
    k_node_mfma<<<(NN + 127) / 128, 256, 0, stream>>>(x, xb, esumx, we1t, wn0t, wn1t, out);
}

// Round 10
// 167.147 us; speedup vs baseline: 8.9244x; 8.9244x over previous
//
#include <hip/hip_runtime.h>
#include <hip/hip_bf16.h>

// Problem constants (from reference)
#define NN 50000
#define NE 800000
#define HD 128
#define NB 391              // buckets of 128 dst nodes: (NN+127)>>7

typedef unsigned short u16;
typedef unsigned char u8;
typedef unsigned int u32;
typedef __attribute__((ext_vector_type(8))) short short8;
typedef __attribute__((ext_vector_type(4))) float floatx4;
typedef __attribute__((ext_vector_type(2))) float f32x2;
#define MFMA __builtin_amdgcn_mfma_f32_16x16x32_bf16

__device__ __forceinline__ float bf2f(u16 v) {
    union { unsigned int u; float f; } x; x.u = ((unsigned int)v) << 16; return x.f;
}
__device__ __forceinline__ u16 f2bf(float f) {
    union { unsigned int u; float f; } x; x.f = f;
    unsigned int r = x.u + 0x7fff + ((x.u >> 16) & 1);
    return (u16)(r >> 16);
}
// fast ELU: t>0 ? t : exp2(t*log2e)-1  (v_exp_f32 path, ~4 instrs)
__device__ __forceinline__ float elu_fast(float t) {
    return t > 0.f ? t : (__builtin_amdgcn_exp2f(t * 1.44269504088896f) - 1.f);
}
// pack 2 f32 -> 2 fp8 (e4m3) in low 16 bits
__device__ __forceinline__ u32 pk_fp8(float a, float b) {
    return __builtin_amdgcn_cvt_pk_fp8_f32(a, b, 0u, false);
}

// convert 8 consecutive f32 to a bf16 A-fragment
__device__ __forceinline__ short8 cvt8(const float* p) {
    const float4* q = (const float4*)p;
    float4 a = q[0], b = q[1];
    short8 r;
    r[0] = (short)f2bf(a.x); r[1] = (short)f2bf(a.y); r[2] = (short)f2bf(a.z); r[3] = (short)f2bf(a.w);
    r[4] = (short)f2bf(b.x); r[5] = (short)f2bf(b.y); r[6] = (short)f2bf(b.z); r[7] = (short)f2bf(b.w);
    return r;
}

// K0: weight prep -> bf16 transposed layouts [c][k]; zeroes bucket counters
__global__ void k_wb(const float* __restrict__ we0, const float* __restrict__ we1,
                     const float* __restrict__ wn0, const float* __restrict__ wn1,
                     u16* __restrict__ wcombt, u16* __restrict__ we1t,
                     u16* __restrict__ wn0t, u16* __restrict__ wn1t,
                     int* __restrict__ gbc) {
    int i = blockIdx.x * 256 + threadIdx.x;
    if (i < 32768) {                       // wcombt
        int c = i >> 7, k = i & 127;
        float v;
        if (c < 128) v = we0[k * 128 + c] + we0[(256 + k) * 128 + c];
        else { int cc = c - 128; v = we0[(128 + k) * 128 + cc] - we0[(256 + k) * 128 + cc]; }
        wcombt[i] = f2bf(v);
    } else if (i < 49152) {                // we1t
        int j = i - 32768; int c = j >> 7, k = j & 127;
        we1t[j] = f2bf(we1[k * 128 + c]);
    } else if (i < 81920) {                // wn0t (k = 0..255)
        int j = i - 49152; int c = j >> 8, k = j & 255;
        wn0t[j] = f2bf(wn0[k * 128 + c]);
    } else if (i < 98304) {                // wn1t
        int j = i - 81920; int c = j >> 7, k = j & 127;
        wn1t[j] = f2bf(wn1[k * 128 + c]);
    } else if (i < 98304 + NB + 1) {       // gbc = 0
        gbc[i - 98304] = 0;
    }
}

// K2: MFMA [P|Q] = x @ Wcomb. 32 rows/block, 4 waves = (2 row-tiles x 2 col-halves).
// p8 (fp8 quads): p8[n][4i+0,1] = P[2i],P[2i+1] ; p8[n][4i+2,3] = x[2i],x[2i+1]
// qb[n][128] = Q (bf16) ; xb[n][128] = x (bf16)
__global__ __launch_bounds__(256) void k_pq_mfma(const float* __restrict__ x,
                                                 const u16* __restrict__ wcombt,
                                                 u8* __restrict__ p8, u16* __restrict__ qb,
                                                 u16* __restrict__ xb) {
    __shared__ u8  pq[32 * 272];
    __shared__ u16 qt[32 * 136];
    int r0 = blockIdx.x * 32;
    int tid = threadIdx.x, wid = tid >> 6, lane = tid & 63;
    int arow = lane & 15, kblk = lane >> 4;
    int rw = (wid & 1) * 16;
    int ch = (wid >> 1) * 128;
    for (int s = tid; s < 32 * 64; s += 256) {
        int r = s >> 6, i = s & 63;
        int n = r0 + r;
        float2 v = (n < NN) ? *(const float2*)&x[(size_t)n * 128 + 2 * i] : make_float2(0.f, 0.f);
        *(u16*)&pq[r * 272 + 4 * i + 2] = (u16)pk_fp8(v.x, v.y);
        if (n < NN) {
            ushort2 o = { f2bf(v.x), f2bf(v.y) };
            *(ushort2*)&xb[(size_t)n * 128 + 2 * i] = o;
        }
    }
    floatx4 acc[8];
#pragma unroll
    for (int n0 = 0; n0 < 8; n0++) acc[n0] = (floatx4)(0.f);
    int nrow = r0 + rw + arow; if (nrow >= NN) nrow = NN - 1;
#pragma unroll
    for (int ks = 0; ks < 4; ks++) {
        short8 a = cvt8(&x[(size_t)nrow * 128 + ks * 32 + kblk * 8]);
#pragma unroll
        for (int n0 = 0; n0 < 8; n0++) {
            short8 b = *(const short8*)&wcombt[(size_t)(ch + n0 * 16 + arow) * 128 + ks * 32 + kblk * 8];
            acc[n0] = MFMA(a, b, acc[n0], 0, 0, 0);
        }
    }
#pragma unroll
    for (int n0 = 0; n0 < 8; n0++) {
#pragma unroll
        for (int j = 0; j < 4; j++) {
            int r = rw + kblk * 4 + j;
            int col = ch + n0 * 16 + arow;
            if (ch == 0) {
                u32 pk = pk_fp8(acc[n0][j], acc[n0][j]);
                pq[r * 272 + 4 * (col >> 1) + (col & 1)] = (u8)pk;
            } else {
                qt[r * 136 + (col - 128)] = f2bf(acc[n0][j]);
            }
        }
    }
    __syncthreads();
    for (int s = tid; s < 32 * 16; s += 256) {
        int r = s >> 4, cb = (s & 15) * 16;
        int n = r0 + r;
        if (n < NN) *(short8*)&p8[(size_t)n * 256 + cb] = *(const short8*)&pq[r * 272 + cb];
    }
    for (int s = tid; s < 32 * 16; s += 256) {
        int r = s >> 4, cb = (s & 15) * 8;
        int n = r0 + r;
        if (n < NN) *(short8*)&qb[(size_t)n * 128 + cb] = *(const short8*)&qt[r * 136 + cb];
    }
}

// K3: bucket histogram (LDS-first). 16 edges/thread, 4096/block.
__global__ __launch_bounds__(256) void k_bhist(const int* __restrict__ ei, int* __restrict__ gbc) {
    __shared__ int bh[NB];
    int tid = threadIdx.x;
    int bs = blockIdx.x * 4096;
    for (int t = tid; t < NB; t += 256) bh[t] = 0;
    __syncthreads();
#pragma unroll
    for (int k = 0; k < 4; k++) {
        int e = bs + k * 1024 + tid * 4;
        if (e < NE) {
            int4 d = *(const int4*)&ei[NE + e];
            atomicAdd(&bh[d.x >> 7], 1); atomicAdd(&bh[d.y >> 7], 1);
            atomicAdd(&bh[d.z >> 7], 1); atomicAdd(&bh[d.w >> 7], 1);
        }
    }
    __syncthreads();
    for (int t = tid; t < NB; t += 256)
        if (bh[t]) atomicAdd(&gbc[t], bh[t]);
}

// K4: scan bucket counts -> boffs[NB+1], gcursor[b] = boffs[b]. One block.
__global__ __launch_bounds__(512) void k_bscan(const int* __restrict__ gbc,
                                               int* __restrict__ boffs, int* __restrict__ gcursor) {
    __shared__ int s[512];
    int t = threadIdx.x;
    int v = (t < NB) ? gbc[t] : 0;
    s[t] = v; __syncthreads();
    for (int off = 1; off < 512; off <<= 1) {
        int tv = (t >= off) ? s[t - off] : 0;
        __syncthreads();
        s[t] += tv; __syncthreads();
    }
    if (t < NB) {
        boffs[t + 1] = s[t];
        gcursor[t] = s[t] - v;
        if (t == 0) boffs[0] = 0;
    }
}

// K5: bucket scatter. 8192 edges/block, 32/thread.
// phases: LDS hist -> reserve global runs -> write packed u32 (src | dl<<16).
__global__ __launch_bounds__(256) void k_bscat(const int* __restrict__ ei,
                                               int* __restrict__ gcursor, u32* __restrict__ ebuf) {
    __shared__ int lh[NB], lbase[NB], lrank[NB];
    int tid = threadIdx.x;
    int bs = blockIdx.x * 8192;
    for (int t = tid; t < NB; t += 256) { lh[t] = 0; lrank[t] = 0; }
    __syncthreads();
    int srcv[32], dstv[32];
#pragma unroll
    for (int k = 0; k < 8; k++) {
        int e = bs + k * 1024 + tid * 4;
        int4 s4, d4;
        if (e < NE) { s4 = *(const int4*)&ei[e]; d4 = *(const int4*)&ei[NE + e]; }
        else { s4 = make_int4(0, 0, 0, 0); d4 = make_int4(-1, -1, -1, -1); }
        srcv[4 * k + 0] = s4.x; srcv[4 * k + 1] = s4.y; srcv[4 * k + 2] = s4.z; srcv[4 * k + 3] = s4.w;
        dstv[4 * k + 0] = d4.x; dstv[4 * k + 1] = d4.y; dstv[4 * k + 2] = d4.z; dstv[4 * k + 3] = d4.w;
    }
#pragma unroll
    for (int i = 0; i < 32; i++)
        if (dstv[i] >= 0) atomicAdd(&lh[dstv[i] >> 7], 1);
    __syncthreads();
    for (int t = tid; t < NB; t += 256)
        if (lh[t]) lbase[t] = atomicAdd(&gcursor[t], lh[t]);
    __syncthreads();
#pragma unroll
    for (int i = 0; i < 32; i++) {
        int d = dstv[i];
        if (d >= 0) {
            int b = d >> 7;
            int r = atomicAdd(&lrank[b], 1);
            ebuf[lbase[b] + r] = (u32)srcv[i] | ((u32)(d & 127) << 16);
        }
    }
}

// K6: per-bucket counting sort -> full CSR (offs + srcs). One block per bucket.
// All srcs writes land in a block-exclusive contiguous region (no cross-XCD line bounce).
__global__ __launch_bounds__(256) void k_bsort(const u32* __restrict__ ebuf,
                                               const int* __restrict__ boffs,
                                               int* __restrict__ offs, int* __restrict__ srcs) {
    __shared__ int hist[128], excl[128], cur[128];
    int bb = blockIdx.x;
    int tid = threadIdx.x;
    int beg = boffs[bb], end = boffs[bb + 1];
    if (tid < 128) hist[tid] = 0;
    __syncthreads();
    for (int s = beg + tid; s < end; s += 256)
        atomicAdd(&hist[(ebuf[s] >> 16) & 127], 1);
    __syncthreads();
    if (tid == 0) {
        int run = 0;
        for (int i = 0; i < 128; i++) { excl[i] = run; run += hist[i]; }
    }
    __syncthreads();
    int nodebase = bb * 128;
    if (tid < 128) {
        cur[tid] = beg + excl[tid];
        int n = nodebase + tid;
        if (n < NN) offs[n] = beg + excl[tid];
    }
    if (bb == NB - 1 && tid == 0) offs[NN] = NE;
    __syncthreads();
    for (int s = beg + tid; s < end; s += 256) {
        u32 pe = ebuf[s];
        int dl = (pe >> 16) & 127;
        int pos = atomicAdd(&cur[dl], 1);
        srcs[pos] = (int)(pe & 0xFFFF);
    }
}

// K7 (= round-8 k_agg): one wave per node; fp8 gathers (4 B/lane = 256 B/edge).
// Unmasked full 8-batches + one masked tail batch; index prefetch pipeline.
//   esumx[n][0:128]   = esum/max(cnt,1)
//   esumx[n][128:256] = (xsum - cnt*x[n])/max(cnt,1)
__global__ __launch_bounds__(256) void k_agg(const u8* __restrict__ p8, const u16* __restrict__ qb,
                                             const u16* __restrict__ xb,
                                             const int* __restrict__ offs, const int* __restrict__ srcs,
                                             u16* __restrict__ esumx) {
    const u32* p8r = (const u32*)p8;     // row = 64 dwords
    int wave = threadIdx.x >> 6, lane = threadIdx.x & 63;
    int n = blockIdx.x * 4 + wave;
    if (n >= NN) return;
    int beg = offs[n], end = offs[n + 1];
    ushort2 qv = *(const ushort2*)(qb + (size_t)n * 128 + 2 * lane);
    float q0 = bf2f(qv.x), q1 = bf2f(qv.y);
    float e0 = 0.f, e1 = 0.f, s0 = 0.f, s1 = 0.f;
    int s = beg;
    if (end > beg) {
        int last = end - 1;
        int sr[8];
#pragma unroll
        for (int j = 0; j < 8; j++) { int t = beg + j; sr[j] = srcs[t <= last ? t : last]; }
        // full batches: no masking
        for (; s + 8 <= end; s += 8) {
            u32 d[8];
#pragma unroll
            for (int j = 0; j < 8; j++) d[j] = p8r[(size_t)sr[j] * 64 + lane];
            int nb = s + 8;
            if (nb < end) {                 // prefetch next batch's indices during compute
#pragma unroll
                for (int j = 0; j < 8; j++) { int t = nb + j; sr[j] = srcs[t <= last ? t : last]; }
            }
#pragma unroll
            for (int j = 0; j < 8; j++) {
                f32x2 pp = __builtin_amdgcn_cvt_pk_f32_fp8(d[j], false);
                f32x2 xp = __builtin_amdgcn_cvt_pk_f32_fp8(d[j], true);
                e0 += elu_fast(pp[0] + q0);
                e1 += elu_fast(pp[1] + q1);
                s0 += xp[0]; s1 += xp[1];
            }
        }
        // masked tail batch (indices already clamped in sr)
        if (s < end) {
            u32 d[8];
#pragma unroll
            for (int j = 0; j < 8; j++) d[j] = p8r[(size_t)sr[j] * 64 + lane];
#pragma unroll
            for (int j = 0; j < 8; j++) {
                bool live = (s + j < end);  // wave-uniform
                f32x2 pp = __builtin_amdgcn_cvt_pk_f32_fp8(d[j], false);
                f32x2 xp = __builtin_amdgcn_cvt_pk_f32_fp8(d[j], true);
                float c0 = elu_fast(pp[0] + q0), c1 = elu_fast(pp[1] + q1);
                e0 += live ? c0 : 0.f;
                e1 += live ? c1 : 0.f;
                s0 += live ? xp[0] : 0.f;
                s1 += live ? xp[1] : 0.f;
            }
        }
    }
    float cntf = (float)(end - beg);
    float inv = 1.f / fmaxf(cntf, 1.f);
    ushort2 xo = *(const ushort2*)(xb + (size_t)n * 128 + 2 * lane);  // own x (bf16)
    s0 = (s0 - cntf * bf2f(xo.x)) * inv;
    s1 = (s1 - cntf * bf2f(xo.y)) * inv;
    e0 *= inv; e1 *= inv;
    ushort2 oe = { f2bf(e0), f2bf(e1) };
    ushort2 os = { f2bf(s0), f2bf(s1) };
    *(ushort2*)(esumx + (size_t)n * 256 + 2 * lane) = oe;
    *(ushort2*)(esumx + (size_t)n * 256 + 128 + 2 * lane) = os;
}

// K8: MFMA node MLP. 128 rows/block, 4 waves; wave owns rows end-to-end, no barriers,
// all global inputs prefetched at entry.
__global__ __launch_bounds__(256, 2) void k_node_mfma(const float* __restrict__ x,
                                                      const u16* __restrict__ xb,
                                                      const u16* __restrict__ esumx,
                                                      const u16* __restrict__ we1t,
                                                      const u16* __restrict__ wn0t,
                                                      const u16* __restrict__ wn1t,
                                                      float* __restrict__ out) {
    __shared__ u16 tile[128 * 136];
    int r0 = blockIdx.x * 128;
    int tid = threadIdx.x, wid = tid >> 6, lane = tid & 63;
    int arow = lane & 15, kblk = lane >> 4;
    int rbase = wid * 32;
    int nrow[2];
#pragma unroll
    for (int rt = 0; rt < 2; rt++) {
        int n = r0 + rbase + rt * 16 + arow; if (n >= NN) n = NN - 1;
        nrow[rt] = n;
    }
    short8 stg[8];
#pragma unroll
    for (int t = 0; t < 8; t++) {
        int idx = t * 64 + lane;
        int r = idx >> 4, cb = (idx & 15) * 8;
        int n = r0 + rbase + r; if (n >= NN) n = NN - 1;
        stg[t] = *(const short8*)&esumx[(size_t)n * 256 + 128 + cb];
    }
    short8 a1[2][4], ax[2][4];
#pragma unroll
    for (int rt = 0; rt < 2; rt++)
#pragma unroll
        for (int ks = 0; ks < 4; ks++) {
            a1[rt][ks] = *(const short8*)&esumx[(size_t)nrow[rt] * 256 + ks * 32 + kblk * 8];
            ax[rt][ks] = *(const short8*)&xb[(size_t)nrow[rt] * 128 + ks * 32 + kblk * 8];
        }
#pragma unroll
    for (int t = 0; t < 8; t++) {
        int idx = t * 64 + lane;
        int r = rbase + (idx >> 4), cb = (idx & 15) * 8;
        *(short8*)&tile[r * 136 + cb] = stg[t];
    }
    floatx4 acc[2][8];
#pragma unroll
    for (int rt = 0; rt < 2; rt++)
#pragma unroll
        for (int n0 = 0; n0 < 8; n0++) acc[rt][n0] = (floatx4)(0.f);
#pragma unroll
    for (int ks = 0; ks < 4; ks++)
#pragma unroll
        for (int n0 = 0; n0 < 8; n0++) {
            short8 b = *(const short8*)&we1t[(size_t)(n0 * 16 + arow) * 128 + ks * 32 + kblk * 8];
            acc[0][n0] = MFMA(a1[0][ks], b, acc[0][n0], 0, 0, 0);
            acc[1][n0] = MFMA(a1[1][ks], b, acc[1][n0], 0, 0, 0);
        }
#pragma unroll
    for (int rt = 0; rt < 2; rt++)
#pragma unroll
        for (int n0 = 0; n0 < 8; n0++)
#pragma unroll
            for (int j = 0; j < 4; j++) {
                int rloc = rbase + rt * 16 + kblk * 4 + j;
                int col = n0 * 16 + arow;
                float m = acc[rt][n0][j] + bf2f(tile[rloc * 136 + col]);
                tile[rloc * 136 + col] = f2bf(m);
            }
#pragma unroll
    for (int rt = 0; rt < 2; rt++)
#pragma unroll
        for (int n0 = 0; n0 < 8; n0++) acc[rt][n0] = (floatx4)(0.f);
#pragma unroll
    for (int ks = 0; ks < 4; ks++) {
        short8 am[2];
#pragma unroll
        for (int rt = 0; rt < 2; rt++)
            am[rt] = *(const short8*)&tile[(rbase + rt * 16 + arow) * 136 + ks * 32 + kblk * 8];
#pragma unroll
        for (int n0 = 0; n0 < 8; n0++) {
            short8 bx = *(const short8*)&wn0t[(size_t)(n0 * 16 + arow) * 256 + ks * 32 + kblk * 8];
            short8 bm = *(const short8*)&wn0t[(size_t)(n0 * 16 + arow) * 256 + 128 + ks * 32 + kblk * 8];
#pragma unroll
            for (int rt = 0; rt < 2; rt++) {
                acc[rt][n0] = MFMA(ax[rt][ks], bx, acc[rt][n0], 0, 0, 0);
                acc[rt][n0] = MFMA(am[rt], bm, acc[rt][n0], 0, 0, 0);
            }
        }
    }
#pragma unroll
    for (int rt = 0; rt < 2; rt++)
#pragma unroll
        for (int n0 = 0; n0 < 8; n0++)
#pragma unroll
            for (int j = 0; j < 4; j++) {
                int rloc = rbase + rt * 16 + kblk * 4 + j;
                tile[rloc * 136 + n0 * 16 + arow] = f2bf(elu_fast(acc[rt][n0][j]));
            }
#pragma unroll
    for (int rt = 0; rt < 2; rt++)
#pragma unroll
        for (int n0 = 0; n0 < 8; n0++) acc[rt][n0] = (floatx4)(0.f);
#pragma unroll
    for (int ks = 0; ks < 4; ks++) {
        short8 a[2];
#pragma unroll
        for (int rt = 0; rt < 2; rt++)
            a[rt] = *(const short8*)&tile[(rbase + rt * 16 + arow) * 136 + ks * 32 + kblk * 8];
#pragma unroll
        for (int n0 = 0; n0 < 8; n0++) {
            short8 b = *(const short8*)&wn1t[(size_t)(n0 * 16 + arow) * 128 + ks * 32 + kblk * 8];
            acc[0][n0] = MFMA(a[0], b, acc[0][n0], 0, 0, 0);
            acc[1][n0] = MFMA(a[1], b, acc[1][n0], 0, 0, 0);
        }
    }
#pragma unroll
    for (int rt = 0; rt < 2; rt++)
#pragma unroll
        for (int n0 = 0; n0 < 8; n0++)
#pragma unroll
            for (int j = 0; j < 4; j++)
                tile[(rbase + rt * 16 + kblk * 4 + j) * 136 + n0 * 16 + arow] = f2bf(acc[rt][n0][j]);
#pragma unroll
    for (int t = 0; t < 16; t++) {
        int idx = t * 64 + lane;
        int r = idx >> 5, cb = (idx & 31) * 4;
        int n = r0 + rbase + r;
        if (n < NN) {
            float4 xv = *(const float4*)&x[(size_t)n * 128 + cb];
            ushort4 tv = *(const ushort4*)&tile[(rbase + r) * 136 + cb];
            float4 o = { xv.x + bf2f(tv.x), xv.y + bf2f(tv.y), xv.z + bf2f(tv.z), xv.w + bf2f(tv.w) };
            *(float4*)&out[(size_t)n * 128 + cb] = o;
        }
    }
}

extern "C" void kernel_launch(void* const* d_in, const int* in_sizes, int n_in,
                              void* d_out, int out_size, void* d_ws, size_t ws_size,
                              hipStream_t stream) {
    const float* x       = (const float*)d_in[0];
    const int* ei        = (const int*)d_in[1];   // int64 in reference -> int32 from harness
    const float* we0     = (const float*)d_in[2];
    const float* we1     = (const float*)d_in[3];
    const float* wn0     = (const float*)d_in[4];
    const float* wn1     = (const float*)d_in[5];
    float* out           = (float*)d_out;

    char* w = (char*)d_ws;
    size_t off = 0;
    auto alloc = [&](size_t bytes) -> void* {
        off = (off + 255) & ~(size_t)255;
        void* p = w + off;
        off += bytes;
        return p;
    };
    u16*   wcombt = (u16*)alloc(256 * 128 * sizeof(u16));
    u16*   we1t   = (u16*)alloc(128 * 128 * sizeof(u16));
    u16*   wn0t   = (u16*)alloc(128 * 256 * sizeof(u16));
    u16*   wn1t   = (u16*)alloc(128 * 128 * sizeof(u16));
    u8*    p8     = (u8*)alloc((size_t)NN * 256 * sizeof(u8));
    u16*   qb     = (u16*)alloc((size_t)NN * 128 * sizeof(u16));
    u16*   xb     = (u16*)alloc((size_t)NN * 128 * sizeof(u16));
    u16*   esumx  = (u16*)alloc((size_t)NN * 256 * sizeof(u16));
    int*   gbc    = (int*)alloc((NB + 1) * sizeof(int));
    int*   boffs  = (int*)alloc((NB + 1) * sizeof(int));
    int*   gcursor= (int*)alloc((NB + 1) * sizeof(int));
    u32*   ebuf   = (u32*)alloc((size_t)NE * sizeof(u32));
    int*   offs   = (int*)alloc((size_t)(NN + 1) * sizeof(int));
    int*   srcs   = (int*)alloc((size_t)NE * sizeof(int));
    (void)ws_size; (void)in_sizes; (void)n_in; (void)out_size;  // ~72 MB of d_ws used

    k_wb<<<(98304 + NB + 1 + 255) / 256, 256, 0, stream>>>(we0, we1, wn0, wn1,
                                                           wcombt, we1t, wn0t, wn1t, gbc);
    k_pq_mfma<<<(NN + 31) / 32, 256, 0, stream>>>(x, wcombt, p8, qb, xb);
    k_bhist<<<(NE + 4095) / 4096, 256, 0, stream>>>(ei, gbc);
    k_bscan<<<1, 512, 0, stream>>>(gbc, boffs, gcursor);
    k_bscat<<<(NE + 8191) / 8192, 256, 0, stream>>>(ei, gcursor, ebuf);
    k_bsort<<<NB, 256, 0, stream>>>(ebuf, boffs, offs, srcs);
    k_agg<<<(NN + 3) / 4, 256, 0, stream>>>(p8, qb, xb, offs, srcs, esumx);
    k_node_mfma<<<(NN + 127) / 128, 256, 0, stream>>>(x, xb, esumx, we1t, wn0t, wn1t, out);
}

// Round 11
// 155.385 us; speedup vs baseline: 9.6000x; 1.0757x over previous
//
#include <hip/hip_runtime.h>
#include <hip/hip_bf16.h>

// Problem constants (from reference)
#define NN 50000
#define NE 800000
#define HD 128
#define NB 391              // buckets of 128 dst nodes: (NN+127)>>7
#define CAP 4096            // fixed bucket capacity: mean 2048, sigma ~45 -> +45 sigma

typedef unsigned short u16;
typedef unsigned char u8;
typedef unsigned int u32;
typedef __attribute__((ext_vector_type(8))) short short8;
typedef __attribute__((ext_vector_type(4))) float floatx4;
typedef __attribute__((ext_vector_type(2))) float f32x2;
#define MFMA __builtin_amdgcn_mfma_f32_16x16x32_bf16

__device__ __forceinline__ float bf2f(u16 v) {
    union { unsigned int u; float f; } x; x.u = ((unsigned int)v) << 16; return x.f;
}
__device__ __forceinline__ u16 f2bf(float f) {
    union { unsigned int u; float f; } x; x.f = f;
    unsigned int r = x.u + 0x7fff + ((x.u >> 16) & 1);
    return (u16)(r >> 16);
}
// fast ELU: t>0 ? t : exp2(t*log2e)-1  (v_exp_f32 path)
__device__ __forceinline__ float elu_fast(float t) {
    return t > 0.f ? t : (__builtin_amdgcn_exp2f(t * 1.44269504088896f) - 1.f);
}
// pack 2 f32 -> 2 fp8 (e4m3) in low 16 bits
__device__ __forceinline__ u32 pk_fp8(float a, float b) {
    return __builtin_amdgcn_cvt_pk_fp8_f32(a, b, 0u, false);
}

// convert 8 consecutive f32 to a bf16 A-fragment
__device__ __forceinline__ short8 cvt8(const float* p) {
    const float4* q = (const float4*)p;
    float4 a = q[0], b = q[1];
    short8 r;
    r[0] = (short)f2bf(a.x); r[1] = (short)f2bf(a.y); r[2] = (short)f2bf(a.z); r[3] = (short)f2bf(a.w);
    r[4] = (short)f2bf(b.x); r[5] = (short)f2bf(b.y); r[6] = (short)f2bf(b.z); r[7] = (short)f2bf(b.w);
    return r;
}

// K0: weight prep -> bf16 transposed layouts [c][k]; zeroes per-bucket cursors
__global__ void k_wb(const float* __restrict__ we0, const float* __restrict__ we1,
                     const float* __restrict__ wn0, const float* __restrict__ wn1,
                     u16* __restrict__ wcombt, u16* __restrict__ we1t,
                     u16* __restrict__ wn0t, u16* __restrict__ wn1t,
                     int* __restrict__ gcursor) {
    int i = blockIdx.x * 256 + threadIdx.x;
    if (i < 32768) {                       // wcombt
        int c = i >> 7, k = i & 127;
        float v;
        if (c < 128) v = we0[k * 128 + c] + we0[(256 + k) * 128 + c];
        else { int cc = c - 128; v = we0[(128 + k) * 128 + cc] - we0[(256 + k) * 128 + cc]; }
        wcombt[i] = f2bf(v);
    } else if (i < 49152) {                // we1t
        int j = i - 32768; int c = j >> 7, k = j & 127;
        we1t[j] = f2bf(we1[k * 128 + c]);
    } else if (i < 81920) {                // wn0t (k = 0..255)
        int j = i - 49152; int c = j >> 8, k = j & 255;
        wn0t[j] = f2bf(wn0[k * 128 + c]);
    } else if (i < 98304) {                // wn1t
        int j = i - 81920; int c = j >> 7, k = j & 127;
        wn1t[j] = f2bf(wn1[k * 128 + c]);
    } else if (i < 98304 + NB) {           // gcursor = 0
        gcursor[i - 98304] = 0;
    }
}

// K2: MFMA [P|Q] = x @ Wcomb. 32 rows/block, 4 waves = (2 row-tiles x 2 col-halves).
// p8 (fp8 quads): p8[n][4i+0,1] = P[2i],P[2i+1] ; p8[n][4i+2,3] = x[2i],x[2i+1]
// qb[n][128] = Q (bf16) ; xb[n][128] = x (bf16)
__global__ __launch_bounds__(256) void k_pq_mfma(const float* __restrict__ x,
                                                 const u16* __restrict__ wcombt,
                                                 u8* __restrict__ p8, u16* __restrict__ qb,
                                                 u16* __restrict__ xb) {
    __shared__ u8  pq[32 * 272];
    __shared__ u16 qt[32 * 136];
    int r0 = blockIdx.x * 32;
    int tid = threadIdx.x, wid = tid >> 6, lane = tid & 63;
    int arow = lane & 15, kblk = lane >> 4;
    int rw = (wid & 1) * 16;
    int ch = (wid >> 1) * 128;
    for (int s = tid; s < 32 * 64; s += 256) {
        int r = s >> 6, i = s & 63;
        int n = r0 + r;
        float2 v = (n < NN) ? *(const float2*)&x[(size_t)n * 128 + 2 * i] : make_float2(0.f, 0.f);
        *(u16*)&pq[r * 272 + 4 * i + 2] = (u16)pk_fp8(v.x, v.y);
        if (n < NN) {
            ushort2 o = { f2bf(v.x), f2bf(v.y) };
            *(ushort2*)&xb[(size_t)n * 128 + 2 * i] = o;
        }
    }
    floatx4 acc[8];
#pragma unroll
    for (int n0 = 0; n0 < 8; n0++) acc[n0] = (floatx4)(0.f);
    int nrow = r0 + rw + arow; if (nrow >= NN) nrow = NN - 1;
#pragma unroll
    for (int ks = 0; ks < 4; ks++) {
        short8 a = cvt8(&x[(size_t)nrow * 128 + ks * 32 + kblk * 8]);
#pragma unroll
        for (int n0 = 0; n0 < 8; n0++) {
            short8 b = *(const short8*)&wcombt[(size_t)(ch + n0 * 16 + arow) * 128 + ks * 32 + kblk * 8];
            acc[n0] = MFMA(a, b, acc[n0], 0, 0, 0);
        }
    }
#pragma unroll
    for (int n0 = 0; n0 < 8; n0++) {
#pragma unroll
        for (int j = 0; j < 4; j++) {
            int r = rw + kblk * 4 + j;
            int col = ch + n0 * 16 + arow;
            if (ch == 0) {
                u32 pk = pk_fp8(acc[n0][j], acc[n0][j]);
                pq[r * 272 + 4 * (col >> 1) + (col & 1)] = (u8)pk;
            } else {
                qt[r * 136 + (col - 128)] = f2bf(acc[n0][j]);
            }
        }
    }
    __syncthreads();
    for (int s = tid; s < 32 * 16; s += 256) {
        int r = s >> 4, cb = (s & 15) * 16;
        int n = r0 + r;
        if (n < NN) *(short8*)&p8[(size_t)n * 256 + cb] = *(const short8*)&pq[r * 272 + cb];
    }
    for (int s = tid; s < 32 * 16; s += 256) {
        int r = s >> 4, cb = (s & 15) * 8;
        int n = r0 + r;
        if (n < NN) *(short8*)&qb[(size_t)n * 128 + cb] = *(const short8*)&qt[r * 136 + cb];
    }
}

// K3: bucket scatter into FIXED per-bucket regions (ebuf[b*CAP ...]).
// 8192 edges/block, 32/thread. LDS hist -> reserve region span -> write packed u32.
__global__ __launch_bounds__(256) void k_bscat(const int* __restrict__ ei,
                                               int* __restrict__ gcursor, u32* __restrict__ ebuf) {
    __shared__ int lh[NB], lbase[NB], lrank[NB];
    int tid = threadIdx.x;
    int bs = blockIdx.x * 8192;
    for (int t = tid; t < NB; t += 256) { lh[t] = 0; lrank[t] = 0; }
    __syncthreads();
    int srcv[32], dstv[32];
#pragma unroll
    for (int k = 0; k < 8; k++) {
        int e = bs + k * 1024 + tid * 4;
        int4 s4, d4;
        if (e < NE) { s4 = *(const int4*)&ei[e]; d4 = *(const int4*)&ei[NE + e]; }
        else { s4 = make_int4(0, 0, 0, 0); d4 = make_int4(-1, -1, -1, -1); }
        srcv[4 * k + 0] = s4.x; srcv[4 * k + 1] = s4.y; srcv[4 * k + 2] = s4.z; srcv[4 * k + 3] = s4.w;
        dstv[4 * k + 0] = d4.x; dstv[4 * k + 1] = d4.y; dstv[4 * k + 2] = d4.z; dstv[4 * k + 3] = d4.w;
    }
#pragma unroll
    for (int i = 0; i < 32; i++)
        if (dstv[i] >= 0) atomicAdd(&lh[dstv[i] >> 7], 1);
    __syncthreads();
    for (int t = tid; t < NB; t += 256)
        if (lh[t]) lbase[t] = atomicAdd(&gcursor[t], lh[t]);
    __syncthreads();
#pragma unroll
    for (int i = 0; i < 32; i++) {
        int d = dstv[i];
        if (d >= 0) {
            int b = d >> 7;
            int r = atomicAdd(&lrank[b], 1);
            ebuf[(size_t)b * CAP + lbase[b] + r] = (u32)srcv[i] | ((u32)(d & 127) << 16);
        }
    }
}

// K4: per-bucket counting sort -> per-node [obeg,oend) + srcs (block-exclusive region).
// Zero-pads 8 slack entries so k_agg can prefetch unconditionally.
__global__ __launch_bounds__(256) void k_bsort(const u32* __restrict__ ebuf,
                                               const int* __restrict__ gcursor,
                                               int* __restrict__ obeg, int* __restrict__ oend,
                                               int* __restrict__ srcs) {
    __shared__ int hist[128], excl[128], cur[128];
    int bb = blockIdx.x;
    int tid = threadIdx.x;
    int beg = bb * CAP;
    int cnt = gcursor[bb];
    int end = beg + cnt;
    if (tid < 128) hist[tid] = 0;
    __syncthreads();
    for (int s = beg + tid; s < end; s += 256)
        atomicAdd(&hist[(ebuf[s] >> 16) & 127], 1);
    __syncthreads();
    if (tid == 0) {
        int run = 0;
        for (int i = 0; i < 128; i++) { excl[i] = run; run += hist[i]; }
    }
    __syncthreads();
    int nodebase = bb * 128;
    if (tid < 128) {
        cur[tid] = beg + excl[tid];
        int n = nodebase + tid;
        if (n < NN) {
            obeg[n] = beg + excl[tid];
            oend[n] = beg + excl[tid] + hist[tid];
        }
    }
    if (tid == 0) {
#pragma unroll
        for (int k = 0; k < 8; k++) srcs[end + k] = 0;   // pad: safe prefetch targets
    }
    __syncthreads();
    for (int s = beg + tid; s < end; s += 256) {
        u32 pe = ebuf[s];
        int dl = (pe >> 16) & 127;
        int pos = atomicAdd(&cur[dl], 1);
        srcs[pos] = (int)(pe & 0xFFFF);
    }
}

// K5: one wave per node; fp8 gathers (4 B/lane = 256 B/edge), 32-bit saddr offsets.
// Unmasked full 8-batches + one masked tail batch; unconditional (padded) index prefetch.
//   esumx[n][0:128]   = esum/max(cnt,1)
//   esumx[n][128:256] = (xsum - cnt*x[n])/max(cnt,1)
__global__ __launch_bounds__(256) void k_agg(const u8* __restrict__ p8, const u16* __restrict__ qb,
                                             const u16* __restrict__ xb,
                                             const int* __restrict__ obeg, const int* __restrict__ oend,
                                             const int* __restrict__ srcs,
                                             u16* __restrict__ esumx) {
    const u32* p8r = (const u32*)p8;     // row = 64 dwords; table 12.8 MB -> 32-bit offsets ok
    int wave = threadIdx.x >> 6, lane = threadIdx.x & 63;
    int n = blockIdx.x * 4 + wave;
    if (n >= NN) return;
    int beg = obeg[n], end = oend[n];
    ushort2 qv = *(const ushort2*)(qb + (size_t)n * 128 + 2 * lane);
    float q0 = bf2f(qv.x), q1 = bf2f(qv.y);
    float e0 = 0.f, e1 = 0.f, s0 = 0.f, s1 = 0.f;
    int s = beg;
    if (end > beg) {
        int sr[8];
#pragma unroll
        for (int j = 0; j < 8; j++) sr[j] = srcs[beg + j];         // padded-safe
        for (; s + 8 <= end; s += 8) {
            u32 d[8];
#pragma unroll
            for (int j = 0; j < 8; j++) d[j] = p8r[((u32)sr[j] << 6) + (u32)lane];
            int nb = s + 8;
            if (nb < end) {
#pragma unroll
                for (int j = 0; j < 8; j++) sr[j] = srcs[nb + j];  // padded-safe
            }
#pragma unroll
            for (int j = 0; j < 8; j++) {
                f32x2 pp = __builtin_amdgcn_cvt_pk_f32_fp8(d[j], false);
                f32x2 xp = __builtin_amdgcn_cvt_pk_f32_fp8(d[j], true);
                e0 += elu_fast(pp[0] + q0);
                e1 += elu_fast(pp[1] + q1);
                s0 += xp[0]; s1 += xp[1];
            }
        }
        if (s < end) {   // masked tail batch; pad indices gather node 0 (valid), masked out
            u32 d[8];
#pragma unroll
            for (int j = 0; j < 8; j++) d[j] = p8r[((u32)sr[j] << 6) + (u32)lane];
#pragma unroll
            for (int j = 0; j < 8; j++) {
                bool live = (s + j < end);  // wave-uniform
                f32x2 pp = __builtin_amdgcn_cvt_pk_f32_fp8(d[j], false);
                f32x2 xp = __builtin_amdgcn_cvt_pk_f32_fp8(d[j], true);
                float c0 = elu_fast(pp[0] + q0), c1 = elu_fast(pp[1] + q1);
                e0 += live ? c0 : 0.f;
                e1 += live ? c1 : 0.f;
                s0 += live ? xp[0] : 0.f;
                s1 += live ? xp[1] : 0.f;
            }
        }
    }
    float cntf = (float)(end - beg);
    float inv = 1.f / fmaxf(cntf, 1.f);
    ushort2 xo = *(const ushort2*)(xb + (size_t)n * 128 + 2 * lane);  // own x (bf16)
    s0 = (s0 - cntf * bf2f(xo.x)) * inv;
    s1 = (s1 - cntf * bf2f(xo.y)) * inv;
    e0 *= inv; e1 *= inv;
    ushort2 oe = { f2bf(e0), f2bf(e1) };
    ushort2 os = { f2bf(s0), f2bf(s1) };
    *(ushort2*)(esumx + (size_t)n * 256 + 2 * lane) = oe;
    *(ushort2*)(esumx + (size_t)n * 256 + 128 + 2 * lane) = os;
}

// K6: MFMA node MLP. 128 rows/block, 4 waves; wave owns rows end-to-end, no barriers,
// all global inputs prefetched at entry.
__global__ __launch_bounds__(256, 2) void k_node_mfma(const float* __restrict__ x,
                                                      const u16* __restrict__ xb,
                                                      const u16* __restrict__ esumx,
                                                      const u16* __restrict__ we1t,
                                                      const u16* __restrict__ wn0t,
                                                      const u16* __restrict__ wn1t,
                                                      float* __restrict__ out) {
    __shared__ u16 tile[128 * 136];
    int r0 = blockIdx.x * 128;
    int tid = threadIdx.x, wid = tid >> 6, lane = tid & 63;
    int arow = lane & 15, kblk = lane >> 4;
    int rbase = wid * 32;
    int nrow[2];
#pragma unroll
    for (int rt = 0; rt < 2; rt++) {
        int n = r0 + rbase + rt * 16 + arow; if (n >= NN) n = NN - 1;
        nrow[rt] = n;
    }
    short8 stg[8];
#pragma unroll
    for (int t = 0; t < 8; t++) {
        int idx = t * 64 + lane;
        int r = idx >> 4, cb = (idx & 15) * 8;
        int n = r0 + rbase + r; if (n >= NN) n = NN - 1;
        stg[t] = *(const short8*)&esumx[(size_t)n * 256 + 128 + cb];
    }
    short8 a1[2][4], ax[2][4];
#pragma unroll
    for (int rt = 0; rt < 2; rt++)
#pragma unroll
        for (int ks = 0; ks < 4; ks++) {
            a1[rt][ks] = *(const short8*)&esumx[(size_t)nrow[rt] * 256 + ks * 32 + kblk * 8];
            ax[rt][ks] = *(const short8*)&xb[(size_t)nrow[rt] * 128 + ks * 32 + kblk * 8];
        }
#pragma unroll
    for (int t = 0; t < 8; t++) {
        int idx = t * 64 + lane;
        int r = rbase + (idx >> 4), cb = (idx & 15) * 8;
        *(short8*)&tile[r * 136 + cb] = stg[t];
    }
    floatx4 acc[2][8];
#pragma unroll
    for (int rt = 0; rt < 2; rt++)
#pragma unroll
        for (int n0 = 0; n0 < 8; n0++) acc[rt][n0] = (floatx4)(0.f);
#pragma unroll
    for (int ks = 0; ks < 4; ks++)
#pragma unroll
        for (int n0 = 0; n0 < 8; n0++) {
            short8 b = *(const short8*)&we1t[(size_t)(n0 * 16 + arow) * 128 + ks * 32 + kblk * 8];
            acc[0][n0] = MFMA(a1[0][ks], b, acc[0][n0], 0, 0, 0);
            acc[1][n0] = MFMA(a1[1][ks], b, acc[1][n0], 0, 0, 0);
        }
#pragma unroll
    for (int rt = 0; rt < 2; rt++)
#pragma unroll
        for (int n0 = 0; n0 < 8; n0++)
#pragma unroll
            for (int j = 0; j < 4; j++) {
                int rloc = rbase + rt * 16 + kblk * 4 + j;
                int col = n0 * 16 + arow;
                float m = acc[rt][n0][j] + bf2f(tile[rloc * 136 + col]);
                tile[rloc * 136 + col] = f2bf(m);
            }
#pragma unroll
    for (int rt = 0; rt < 2; rt++)
#pragma unroll
        for (int n0 = 0; n0 < 8; n0++) acc[rt][n0] = (floatx4)(0.f);
#pragma unroll
    for (int ks = 0; ks < 4; ks++) {
        short8 am[2];
#pragma unroll
        for (int rt = 0; rt < 2; rt++)
            am[rt] = *(const short8*)&tile[(rbase + rt * 16 + arow) * 136 + ks * 32 + kblk * 8];
#pragma unroll
        for (int n0 = 0; n0 < 8; n0++) {
            short8 bx = *(const short8*)&wn0t[(size_t)(n0 * 16 + arow) * 256 + ks * 32 + kblk * 8];
            short8 bm = *(const short8*)&wn0t[(size_t)(n0 * 16 + arow) * 256 + 128 + ks * 32 + kblk * 8];
#pragma unroll
            for (int rt = 0; rt < 2; rt++) {
                acc[rt][n0] = MFMA(ax[rt][ks], bx, acc[rt][n0], 0, 0, 0);
                acc[rt][n0] = MFMA(am[rt], bm, acc[rt][n0], 0, 0, 0);
            }
        }
    }
#pragma unroll
    for (int rt = 0; rt < 2; rt++)
#pragma unroll
        for (int n0 = 0; n0 < 8; n0++)
#pragma unroll
            for (int j = 0; j < 4; j++) {
                int rloc = rbase + rt * 16 + kblk * 4 + j;
                tile[rloc * 136 + n0 * 16 + arow] = f2bf(elu_fast(acc[rt][n0][j]));
            }
#pragma unroll
    for (int rt = 0; rt < 2; rt++)
#pragma unroll
        for (int n0 = 0; n0 < 8; n0++) acc[rt][n0] = (floatx4)(0.f);
#pragma unroll
    for (int ks = 0; ks < 4; ks++) {
        short8 a[2];
#pragma unroll
        for (int rt = 0; rt < 2; rt++)
            a[rt] = *(const short8*)&tile[(rbase + rt * 16 + arow) * 136 + ks * 32 + kblk * 8];
#pragma unroll
        for (int n0 = 0; n0 < 8; n0++) {
            short8 b = *(const short8*)&wn1t[(size_t)(n0 * 16 + arow) * 128 + ks * 32 + kblk * 8];
            acc[0][n0] = MFMA(a[0], b, acc[0][n0], 0, 0, 0);
            acc[1][n0] = MFMA(a[1], b, acc[1][n0], 0, 0, 0);
        }
    }
#pragma unroll
    for (int rt = 0; rt < 2; rt++)
#pragma unroll
        for (int n0 = 0; n0 < 8; n0++)
#pragma unroll
            for (int j = 0; j < 4; j++)
                tile[(rbase + rt * 16 + kblk * 4 + j) * 136 + n0 * 16 + arow] = f2bf(acc[rt][n0][j]);
#pragma unroll
    for (int t = 0; t < 16; t++) {
        int idx = t * 64 + lane;
        int r = idx >> 5, cb = (idx & 31) * 4;
        int n = r0 + rbase + r;
        if (n < NN) {
            float4 xv = *(const float4*)&x[(size_t)n * 128 + cb];
            ushort4 tv = *(const ushort4*)&tile[(rbase + r) * 136 + cb];
            float4 o = { xv.x + bf2f(tv.x), xv.y + bf2f(tv.y), xv.z + bf2f(tv.z), xv.w + bf2f(tv.w) };
            *(float4*)&out[(size_t)n * 128 + cb] = o;
        }
    }
}

extern "C" void kernel_launch(void* const* d_in, const int* in_sizes, int n_in,
                              void* d_out, int out_size, void* d_ws, size_t ws_size,
                              hipStream_t stream) {
    const float* x       = (const float*)d_in[0];
    const int* ei        = (const int*)d_in[1];   // int64 in reference -> int32 from harness
    const float* we0     = (const float*)d_in[2];
    const float* we1     = (const float*)d_in[3];
    const float* wn0     = (const float*)d_in[4];
    const float* wn1     = (const float*)d_in[5];
    float* out           = (float*)d_out;

    char* w = (char*)d_ws;
    size_t off = 0;
    auto alloc = [&](size_t bytes) -> void* {
        off = (off + 255) & ~(size_t)255;
        void* p = w + off;
        off += bytes;
        return p;
    };
    u16*   wcombt = (u16*)alloc(256 * 128 * sizeof(u16));
    u16*   we1t   = (u16*)alloc(128 * 128 * sizeof(u16));
    u16*   wn0t   = (u16*)alloc(128 * 256 * sizeof(u16));
    u16*   wn1t   = (u16*)alloc(128 * 128 * sizeof(u16));
    u8*    p8     = (u8*)alloc((size_t)NN * 256 * sizeof(u8));
    u16*   qb     = (u16*)alloc((size_t)NN * 128 * sizeof(u16));
    u16*   xb     = (u16*)alloc((size_t)NN * 128 * sizeof(u16));
    u16*   esumx  = (u16*)alloc((size_t)NN * 256 * sizeof(u16));
    int*   gcursor= (int*)alloc(NB * sizeof(int));
    u32*   ebuf   = (u32*)alloc((size_t)NB * CAP * sizeof(u32));
    int*   obeg   = (int*)alloc((size_t)NN * sizeof(int));
    int*   oend   = (int*)alloc((size_t)NN * sizeof(int));
    int*   srcs   = (int*)alloc(((size_t)NB * CAP + 64) * sizeof(int));
    (void)ws_size; (void)in_sizes; (void)n_in; (void)out_size;  // ~78 MB of d_ws used

    k_wb<<<(98304 + NB + 255) / 256, 256, 0, stream>>>(we0, we1, wn0, wn1,
                                                       wcombt, we1t, wn0t, wn1t, gcursor);
    k_pq_mfma<<<(NN + 31) / 32, 256, 0, stream>>>(x, wcombt, p8, qb, xb);
    k_bscat<<<(NE + 8191) / 8192, 256, 0, stream>>>(ei, gcursor, ebuf);
    k_bsort<<<NB, 256, 0, stream>>>(ebuf, gcursor, obeg, oend, srcs);
    k_agg<<<(NN + 3) / 4, 256, 0, stream>>>(p8, qb, xb, obeg, oend, srcs, esumx);
    k_node_mfma<<<(NN + 127) / 128, 256, 0, stream>>>(x, xb, esumx, we1t, wn0t, wn1t, out);
}

// Round 12
// 154.109 us; speedup vs baseline: 9.6795x; 1.0083x over previous
//
#include <hip/hip_runtime.h>
#include <hip/hip_bf16.h>

// Problem constants (from reference)
#define NN 50000
#define NE 800000
#define HD 128
#define NB 391              // buckets of 128 dst nodes: (NN+127)>>7
#define CAP 4096            // fixed bucket capacity: mean 2048, sigma ~45 -> +45 sigma

typedef unsigned short u16;
typedef unsigned char u8;
typedef unsigned int u32;
typedef __attribute__((ext_vector_type(8))) short short8;
typedef __attribute__((ext_vector_type(4))) float floatx4;
typedef __attribute__((ext_vector_type(2))) float f32x2;
#define MFMA __builtin_amdgcn_mfma_f32_16x16x32_bf16

__device__ __forceinline__ float bf2f(u16 v) {
    union { unsigned int u; float f; } x; x.u = ((unsigned int)v) << 16; return x.f;
}
__device__ __forceinline__ u16 f2bf(float f) {
    union { unsigned int u; float f; } x; x.f = f;
    unsigned int r = x.u + 0x7fff + ((x.u >> 16) & 1);
    return (u16)(r >> 16);
}
// fast ELU: t>0 ? t : exp2(t*log2e)-1  (v_exp_f32 path)
__device__ __forceinline__ float elu_fast(float t) {
    return t > 0.f ? t : (__builtin_amdgcn_exp2f(t * 1.44269504088896f) - 1.f);
}
// pack 2 f32 -> 2 fp8 (e4m3) in low 16 bits
__device__ __forceinline__ u32 pk_fp8(float a, float b) {
    return __builtin_amdgcn_cvt_pk_fp8_f32(a, b, 0u, false);
}

// K0: weight prep -> bf16 transposed layouts [c][k]; zeroes per-bucket cursors
__global__ void k_wb(const float* __restrict__ we0, const float* __restrict__ we1,
                     const float* __restrict__ wn0, const float* __restrict__ wn1,
                     u16* __restrict__ wcombt, u16* __restrict__ we1t,
                     u16* __restrict__ wn0t, u16* __restrict__ wn1t,
                     int* __restrict__ gcursor) {
    int i = blockIdx.x * 256 + threadIdx.x;
    if (i < 32768) {                       // wcombt
        int c = i >> 7, k = i & 127;
        float v;
        if (c < 128) v = we0[k * 128 + c] + we0[(256 + k) * 128 + c];
        else { int cc = c - 128; v = we0[(128 + k) * 128 + cc] - we0[(256 + k) * 128 + cc]; }
        wcombt[i] = f2bf(v);
    } else if (i < 49152) {                // we1t
        int j = i - 32768; int c = j >> 7, k = j & 127;
        we1t[j] = f2bf(we1[k * 128 + c]);
    } else if (i < 81920) {                // wn0t (k = 0..255)
        int j = i - 49152; int c = j >> 8, k = j & 255;
        wn0t[j] = f2bf(wn0[k * 128 + c]);
    } else if (i < 98304) {                // wn1t
        int j = i - 81920; int c = j >> 7, k = j & 127;
        wn1t[j] = f2bf(wn1[k * 128 + c]);
    } else if (i < 98304 + NB) {           // gcursor = 0
        gcursor[i - 98304] = 0;
    }
}

// K2 v6: MFMA [P|Q] = x @ Wcomb. 64 rows/block, 4 waves; wave owns 16 rows end-to-end.
// Per lane: prefetch its row's 32 x-floats ONCE; derive A-frags (bf16), xb (bf16),
// and fp8 x-slots from registers. 64 MFMAs/wave. One barrier before coalesced flush.
// p8 (fp8 quads): p8[n][4i+0,1] = P[2i],P[2i+1] ; p8[n][4i+2,3] = x[2i],x[2i+1]
// qb[n][128] = Q (bf16) ; xb[n][128] = x (bf16)
__global__ __launch_bounds__(256) void k_pq_mfma(const float* __restrict__ x,
                                                 const u16* __restrict__ wcombt,
                                                 u8* __restrict__ p8, u16* __restrict__ qb,
                                                 u16* __restrict__ xb) {
    __shared__ u8  pq[64 * 272];   // fp8 quad tile (256 B/row + pad)
    __shared__ u16 qt[64 * 136];   // Q tile (bf16)
    int r0 = blockIdx.x * 64;
    int tid = threadIdx.x, wid = tid >> 6, lane = tid & 63;
    int arow = lane & 15, kblk = lane >> 4;
    int row_local = wid * 16 + arow;                 // 0..63
    int nrow = r0 + row_local; if (nrow >= NN) nrow = NN - 1;
    const float* xrow = &x[(size_t)nrow * 128];

    // ---- single global read of this lane's x share (4 ks-chunks x 8 floats) ----
    float4 xf[8];
#pragma unroll
    for (int ks = 0; ks < 4; ks++) {
        xf[2 * ks]     = *(const float4*)&xrow[ks * 32 + kblk * 8];
        xf[2 * ks + 1] = *(const float4*)&xrow[ks * 32 + kblk * 8 + 4];
    }
    const float* xfp = (const float*)xf;
    // A-frags (bf16) + xb store (16 B per ks)
    short8 a[4];
#pragma unroll
    for (int ks = 0; ks < 4; ks++) {
        short8 r;
#pragma unroll
        for (int j = 0; j < 8; j++) r[j] = (short)f2bf(xfp[ks * 8 + j]);
        a[ks] = r;
        *(short8*)&xb[(size_t)nrow * 128 + ks * 32 + kblk * 8] = r;
    }
    // fp8 x-slots into LDS quad layout
#pragma unroll
    for (int ks = 0; ks < 4; ks++)
#pragma unroll
        for (int m = 0; m < 4; m++) {
            u16 v = (u16)pk_fp8(xfp[ks * 8 + 2 * m], xfp[ks * 8 + 2 * m + 1]);
            *(u16*)&pq[row_local * 272 + 4 * (ks * 16 + kblk * 4 + m) + 2] = v;
        }

    // ---- MFMA: 16 col-tiles x 4 k-steps ----
    floatx4 acc[16];
#pragma unroll
    for (int n0 = 0; n0 < 16; n0++) acc[n0] = (floatx4)(0.f);
#pragma unroll
    for (int ks = 0; ks < 4; ks++)
#pragma unroll
        for (int n0 = 0; n0 < 16; n0++) {
            short8 b = *(const short8*)&wcombt[(size_t)(n0 * 16 + arow) * 128 + ks * 32 + kblk * 8];
            acc[n0] = MFMA(a[ks], b, acc[n0], 0, 0, 0);
        }

    // ---- epilogue into LDS (own wave's rows; n0 split is compile-time uniform) ----
#pragma unroll
    for (int n0 = 0; n0 < 16; n0++)
#pragma unroll
        for (int j = 0; j < 4; j++) {
            int r = wid * 16 + kblk * 4 + j;
            int col = n0 * 16 + arow;
            float v = acc[n0][j];
            if (n0 < 8) pq[r * 272 + 4 * (col >> 1) + (col & 1)] = (u8)pk_fp8(v, v);
            else        qt[r * 136 + (col - 128)] = f2bf(v);
        }
    __syncthreads();
    // ---- coalesced flush ----
    for (int s = tid; s < 64 * 16; s += 256) {
        int r = s >> 4, cb = (s & 15) * 16;
        int n = r0 + r;
        if (n < NN) *(short8*)&p8[(size_t)n * 256 + cb] = *(const short8*)&pq[r * 272 + cb];
    }
    for (int s = tid; s < 64 * 16; s += 256) {
        int r = s >> 4, cb = (s & 15) * 8;
        int n = r0 + r;
        if (n < NN) *(short8*)&qb[(size_t)n * 128 + cb] = *(const short8*)&qt[r * 136 + cb];
    }
}

// K3: bucket scatter into FIXED per-bucket regions (ebuf[b*CAP ...]).
// 8192 edges/block, 32/thread. LDS hist -> reserve region span -> write packed u32.
__global__ __launch_bounds__(256) void k_bscat(const int* __restrict__ ei,
                                               int* __restrict__ gcursor, u32* __restrict__ ebuf) {
    __shared__ int lh[NB], lbase[NB], lrank[NB];
    int tid = threadIdx.x;
    int bs = blockIdx.x * 8192;
    for (int t = tid; t < NB; t += 256) { lh[t] = 0; lrank[t] = 0; }
    __syncthreads();
    int srcv[32], dstv[32];
#pragma unroll
    for (int k = 0; k < 8; k++) {
        int e = bs + k * 1024 + tid * 4;
        int4 s4, d4;
        if (e < NE) { s4 = *(const int4*)&ei[e]; d4 = *(const int4*)&ei[NE + e]; }
        else { s4 = make_int4(0, 0, 0, 0); d4 = make_int4(-1, -1, -1, -1); }
        srcv[4 * k + 0] = s4.x; srcv[4 * k + 1] = s4.y; srcv[4 * k + 2] = s4.z; srcv[4 * k + 3] = s4.w;
        dstv[4 * k + 0] = d4.x; dstv[4 * k + 1] = d4.y; dstv[4 * k + 2] = d4.z; dstv[4 * k + 3] = d4.w;
    }
#pragma unroll
    for (int i = 0; i < 32; i++)
        if (dstv[i] >= 0) atomicAdd(&lh[dstv[i] >> 7], 1);
    __syncthreads();
    for (int t = tid; t < NB; t += 256)
        if (lh[t]) lbase[t] = atomicAdd(&gcursor[t], lh[t]);
    __syncthreads();
#pragma unroll
    for (int i = 0; i < 32; i++) {
        int d = dstv[i];
        if (d >= 0) {
            int b = d >> 7;
            int r = atomicAdd(&lrank[b], 1);
            ebuf[(size_t)b * CAP + lbase[b] + r] = (u32)srcv[i] | ((u32)(d & 127) << 16);
        }
    }
}

// K4: per-bucket counting sort -> per-node [obeg,oend) + srcs (block-exclusive region).
// Zero-pads 8 slack entries so k_agg can prefetch unconditionally.
__global__ __launch_bounds__(256) void k_bsort(const u32* __restrict__ ebuf,
                                               const int* __restrict__ gcursor,
                                               int* __restrict__ obeg, int* __restrict__ oend,
                                               int* __restrict__ srcs) {
    __shared__ int hist[128], excl[128], cur[128];
    int bb = blockIdx.x;
    int tid = threadIdx.x;
    int beg = bb * CAP;
    int cnt = gcursor[bb];
    int end = beg + cnt;
    if (tid < 128) hist[tid] = 0;
    __syncthreads();
    for (int s = beg + tid; s < end; s += 256)
        atomicAdd(&hist[(ebuf[s] >> 16) & 127], 1);
    __syncthreads();
    if (tid == 0) {
        int run = 0;
        for (int i = 0; i < 128; i++) { excl[i] = run; run += hist[i]; }
    }
    __syncthreads();
    int nodebase = bb * 128;
    if (tid < 128) {
        cur[tid] = beg + excl[tid];
        int n = nodebase + tid;
        if (n < NN) {
            obeg[n] = beg + excl[tid];
            oend[n] = beg + excl[tid] + hist[tid];
        }
    }
    if (tid == 0) {
#pragma unroll
        for (int k = 0; k < 8; k++) srcs[end + k] = 0;   // pad: safe prefetch targets
    }
    __syncthreads();
    for (int s = beg + tid; s < end; s += 256) {
        u32 pe = ebuf[s];
        int dl = (pe >> 16) & 127;
        int pos = atomicAdd(&cur[dl], 1);
        srcs[pos] = (int)(pe & 0xFFFF);
    }
}

// K5: one wave per node; fp8 gathers (4 B/lane = 256 B/edge), 32-bit saddr offsets.
// Unmasked full 8-batches + one masked tail batch; unconditional (padded) index prefetch.
//   esumx[n][0:128]   = esum/max(cnt,1)
//   esumx[n][128:256] = (xsum - cnt*x[n])/max(cnt,1)
__global__ __launch_bounds__(256) void k_agg(const u8* __restrict__ p8, const u16* __restrict__ qb,
                                             const u16* __restrict__ xb,
                                             const int* __restrict__ obeg, const int* __restrict__ oend,
                                             const int* __restrict__ srcs,
                                             u16* __restrict__ esumx) {
    const u32* p8r = (const u32*)p8;     // row = 64 dwords; table 12.8 MB -> 32-bit offsets ok
    int wave = threadIdx.x >> 6, lane = threadIdx.x & 63;
    int n = blockIdx.x * 4 + wave;
    if (n >= NN) return;
    int beg = obeg[n], end = oend[n];
    ushort2 qv = *(const ushort2*)(qb + (size_t)n * 128 + 2 * lane);
    float q0 = bf2f(qv.x), q1 = bf2f(qv.y);
    float e0 = 0.f, e1 = 0.f, s0 = 0.f, s1 = 0.f;
    int s = beg;
    if (end > beg) {
        int sr[8];
#pragma unroll
        for (int j = 0; j < 8; j++) sr[j] = srcs[beg + j];         // padded-safe
        for (; s + 8 <= end; s += 8) {
            u32 d[8];
#pragma unroll
            for (int j = 0; j < 8; j++) d[j] = p8r[((u32)sr[j] << 6) + (u32)lane];
            int nb = s + 8;
            if (nb < end) {
#pragma unroll
                for (int j = 0; j < 8; j++) sr[j] = srcs[nb + j];  // padded-safe
            }
#pragma unroll
            for (int j = 0; j < 8; j++) {
                f32x2 pp = __builtin_amdgcn_cvt_pk_f32_fp8(d[j], false);
                f32x2 xp = __builtin_amdgcn_cvt_pk_f32_fp8(d[j], true);
                e0 += elu_fast(pp[0] + q0);
                e1 += elu_fast(pp[1] + q1);
                s0 += xp[0]; s1 += xp[1];
            }
        }
        if (s < end) {   // masked tail batch; pad indices gather node 0 (valid), masked out
            u32 d[8];
#pragma unroll
            for (int j = 0; j < 8; j++) d[j] = p8r[((u32)sr[j] << 6) + (u32)lane];
#pragma unroll
            for (int j = 0; j < 8; j++) {
                bool live = (s + j < end);  // wave-uniform
                f32x2 pp = __builtin_amdgcn_cvt_pk_f32_fp8(d[j], false);
                f32x2 xp = __builtin_amdgcn_cvt_pk_f32_fp8(d[j], true);
                float c0 = elu_fast(pp[0] + q0), c1 = elu_fast(pp[1] + q1);
                e0 += live ? c0 : 0.f;
                e1 += live ? c1 : 0.f;
                s0 += live ? xp[0] : 0.f;
                s1 += live ? xp[1] : 0.f;
            }
        }
    }
    float cntf = (float)(end - beg);
    float inv = 1.f / fmaxf(cntf, 1.f);
    ushort2 xo = *(const ushort2*)(xb + (size_t)n * 128 + 2 * lane);  // own x (bf16)
    s0 = (s0 - cntf * bf2f(xo.x)) * inv;
    s1 = (s1 - cntf * bf2f(xo.y)) * inv;
    e0 *= inv; e1 *= inv;
    ushort2 oe = { f2bf(e0), f2bf(e1) };
    ushort2 os = { f2bf(s0), f2bf(s1) };
    *(ushort2*)(esumx + (size_t)n * 256 + 2 * lane) = oe;
    *(ushort2*)(esumx + (size_t)n * 256 + 128 + 2 * lane) = os;
}

// K6: MFMA node MLP. 128 rows/block, 4 waves; wave owns rows end-to-end, no barriers,
// all global inputs prefetched at entry.
__global__ __launch_bounds__(256, 2) void k_node_mfma(const float* __restrict__ x,
                                                      const u16* __restrict__ xb,
                                                      const u16* __restrict__ esumx,
                                                      const u16* __restrict__ we1t,
                                                      const u16* __restrict__ wn0t,
                                                      const u16* __restrict__ wn1t,
                                                      float* __restrict__ out) {
    __shared__ u16 tile[128 * 136];
    int r0 = blockIdx.x * 128;
    int tid = threadIdx.x, wid = tid >> 6, lane = tid & 63;
    int arow = lane & 15, kblk = lane >> 4;
    int rbase = wid * 32;
    int nrow[2];
#pragma unroll
    for (int rt = 0; rt < 2; rt++) {
        int n = r0 + rbase + rt * 16 + arow; if (n >= NN) n = NN - 1;
        nrow[rt] = n;
    }
    short8 stg[8];
#pragma unroll
    for (int t = 0; t < 8; t++) {
        int idx = t * 64 + lane;
        int r = idx >> 4, cb = (idx & 15) * 8;
        int n = r0 + rbase + r; if (n >= NN) n = NN - 1;
        stg[t] = *(const short8*)&esumx[(size_t)n * 256 + 128 + cb];
    }
    short8 a1[2][4], ax[2][4];
#pragma unroll
    for (int rt = 0; rt < 2; rt++)
#pragma unroll
        for (int ks = 0; ks < 4; ks++) {
            a1[rt][ks] = *(const short8*)&esumx[(size_t)nrow[rt] * 256 + ks * 32 + kblk * 8];
            ax[rt][ks] = *(const short8*)&xb[(size_t)nrow[rt] * 128 + ks * 32 + kblk * 8];
        }
#pragma unroll
    for (int t = 0; t < 8; t++) {
        int idx = t * 64 + lane;
        int r = rbase + (idx >> 4), cb = (idx & 15) * 8;
        *(short8*)&tile[r * 136 + cb] = stg[t];
    }
    floatx4 acc[2][8];
#pragma unroll
    for (int rt = 0; rt < 2; rt++)
#pragma unroll
        for (int n0 = 0; n0 < 8; n0++) acc[rt][n0] = (floatx4)(0.f);
#pragma unroll
    for (int ks = 0; ks < 4; ks++)
#pragma unroll
        for (int n0 = 0; n0 < 8; n0++) {
            short8 b = *(const short8*)&we1t[(size_t)(n0 * 16 + arow) * 128 + ks * 32 + kblk * 8];
            acc[0][n0] = MFMA(a1[0][ks], b, acc[0][n0], 0, 0, 0);
            acc[1][n0] = MFMA(a1[1][ks], b, acc[1][n0], 0, 0, 0);
        }
#pragma unroll
    for (int rt = 0; rt < 2; rt++)
#pragma unroll
        for (int n0 = 0; n0 < 8; n0++)
#pragma unroll
            for (int j = 0; j < 4; j++) {
                int rloc = rbase + rt * 16 + kblk * 4 + j;
                int col = n0 * 16 + arow;
                float m = acc[rt][n0][j] + bf2f(tile[rloc * 136 + col]);
                tile[rloc * 136 + col] = f2bf(m);
            }
#pragma unroll
    for (int rt = 0; rt < 2; rt++)
#pragma unroll
        for (int n0 = 0; n0 < 8; n0++) acc[rt][n0] = (floatx4)(0.f);
#pragma unroll
    for (int ks = 0; ks < 4; ks++) {
        short8 am[2];
#pragma unroll
        for (int rt = 0; rt < 2; rt++)
            am[rt] = *(const short8*)&tile[(rbase + rt * 16 + arow) * 136 + ks * 32 + kblk * 8];
#pragma unroll
        for (int n0 = 0; n0 < 8; n0++) {
            short8 bx = *(const short8*)&wn0t[(size_t)(n0 * 16 + arow) * 256 + ks * 32 + kblk * 8];
            short8 bm = *(const short8*)&wn0t[(size_t)(n0 * 16 + arow) * 256 + 128 + ks * 32 + kblk * 8];
#pragma unroll
            for (int rt = 0; rt < 2; rt++) {
                acc[rt][n0] = MFMA(ax[rt][ks], bx, acc[rt][n0], 0, 0, 0);
                acc[rt][n0] = MFMA(am[rt], bm, acc[rt][n0], 0, 0, 0);
            }
        }
    }
#pragma unroll
    for (int rt = 0; rt < 2; rt++)
#pragma unroll
        for (int n0 = 0; n0 < 8; n0++)
#pragma unroll
            for (int j = 0; j < 4; j++) {
                int rloc = rbase + rt * 16 + kblk * 4 + j;
                tile[rloc * 136 + n0 * 16 + arow] = f2bf(elu_fast(acc[rt][n0][j]));
            }
#pragma unroll
    for (int rt = 0; rt < 2; rt++)
#pragma unroll
        for (int n0 = 0; n0 < 8; n0++) acc[rt][n0] = (floatx4)(0.f);
#pragma unroll
    for (int ks = 0; ks < 4; ks++) {
        short8 a[2];
#pragma unroll
        for (int rt = 0; rt < 2; rt++)
            a[rt] = *(const short8*)&tile[(rbase + rt * 16 + arow) * 136 + ks * 32 + kblk * 8];
#pragma unroll
        for (int n0 = 0; n0 < 8; n0++) {
            short8 b = *(const short8*)&wn1t[(size_t)(n0 * 16 + arow) * 128 + ks * 32 + kblk * 8];
            acc[0][n0] = MFMA(a[0], b, acc[0][n0], 0, 0, 0);
            acc[1][n0] = MFMA(a[1], b, acc[1][n0], 0, 0, 0);
        }
    }
#pragma unroll
    for (int rt = 0; rt < 2; rt++)
#pragma unroll
        for (int n0 = 0; n0 < 8; n0++)
#pragma unroll
            for (int j = 0; j < 4; j++)
                tile[(rbase + rt * 16 + kblk * 4 + j) * 136 + n0 * 16 + arow] = f2bf(acc[rt][n0][j]);
#pragma unroll
    for (int t = 0; t < 16; t++) {
        int idx = t * 64 + lane;
        int r = idx >> 5, cb = (idx & 31) * 4;
        int n = r0 + rbase + r;
        if (n < NN) {
            float4 xv = *(const float4*)&x[(size_t)n * 128 + cb];
            ushort4 tv = *(const ushort4*)&tile[(rbase + r) * 136 + cb];
            float4 o = { xv.x + bf2f(tv.x), xv.y + bf2f(tv.y), xv.z + bf2f(tv.z), xv.w + bf2f(tv.w) };
            *(float4*)&out[(size_t)n * 128 + cb] = o;
        }
    }
}

extern "C" void kernel_launch(void* const* d_in, const int* in_sizes, int n_in,
                              void* d_out, int out_size, void* d_ws, size_t ws_size,
                              hipStream_t stream) {
    const float* x       = (const float*)d_in[0];
    const int* ei        = (const int*)d_in[1];   // int64 in reference -> int32 from harness
    const float* we0     = (const float*)d_in[2];
    const float* we1     = (const float*)d_in[3];
    const float* wn0     = (const float*)d_in[4];
    const float* wn1     = (const float*)d_in[5];
    float* out           = (float*)d_out;

    char* w = (char*)d_ws;
    size_t off = 0;
    auto alloc = [&](size_t bytes) -> void* {
        off = (off + 255) & ~(size_t)255;
        void* p = w + off;
        off += bytes;
        return p;
    };
    u16*   wcombt = (u16*)alloc(256 * 128 * sizeof(u16));
    u16*   we1t   = (u16*)alloc(128 * 128 * sizeof(u16));
    u16*   wn0t   = (u16*)alloc(128 * 256 * sizeof(u16));
    u16*   wn1t   = (u16*)alloc(128 * 128 * sizeof(u16));
    u8*    p8     = (u8*)alloc((size_t)NN * 256 * sizeof(u8));
    u16*   qb     = (u16*)alloc((size_t)NN * 128 * sizeof(u16));
    u16*   xb     = (u16*)alloc((size_t)NN * 128 * sizeof(u16));
    u16*   esumx  = (u16*)alloc((size_t)NN * 256 * sizeof(u16));
    int*   gcursor= (int*)alloc(NB * sizeof(int));
    u32*   ebuf   = (u32*)alloc((size_t)NB * CAP * sizeof(u32));
    int*   obeg   = (int*)alloc((size_t)NN * sizeof(int));
    int*   oend   = (int*)alloc((size_t)NN * sizeof(int));
    int*   srcs   = (int*)alloc(((size_t)NB * CAP + 64) * sizeof(int));
    (void)ws_size; (void)in_sizes; (void)n_in; (void)out_size;  // ~78 MB of d_ws used

    k_wb<<<(98304 + NB + 255) / 256, 256, 0, stream>>>(we0, we1, wn0, wn1,
                                                       wcombt, we1t, wn0t, wn1t, gcursor);
    k_pq_mfma<<<(NN + 63) / 64, 256, 0, stream>>>(x, wcombt, p8, qb, xb);
    k_bscat<<<(NE + 8191) / 8192, 256, 0, stream>>>(ei, gcursor, ebuf);
    k_bsort<<<NB, 256, 0, stream>>>(ebuf, gcursor, obeg, oend, srcs);
    k_agg<<<(NN + 3) / 4, 256, 0, stream>>>(p8, qb, xb, obeg, oend, srcs, esumx);
    k_node_mfma<<<(NN + 127) / 128, 256, 0, stream>>>(x, xb, esumx, we1t, wn0t, wn1t, out);
}

// Round 13
// 152.565 us; speedup vs baseline: 9.7774x; 1.0101x over previous
//
#include <hip/hip_runtime.h>
#include <hip/hip_bf16.h>

// Problem constants (from reference)
#define NN 50000
#define NE 800000
#define HD 128
#define NB 391              // buckets of 128 dst nodes: (NN+127)>>7
#define CAP 4096            // fixed bucket capacity: mean 2048, sigma ~45 -> +45 sigma

typedef unsigned short u16;
typedef unsigned char u8;
typedef unsigned int u32;
typedef __attribute__((ext_vector_type(8))) short short8;
typedef __attribute__((ext_vector_type(4))) float floatx4;
typedef __attribute__((ext_vector_type(2))) float f32x2;
#define MFMA __builtin_amdgcn_mfma_f32_16x16x32_bf16

__device__ __forceinline__ float bf2f(u16 v) {
    union { unsigned int u; float f; } x; x.u = ((unsigned int)v) << 16; return x.f;
}
__device__ __forceinline__ u16 f2bf(float f) {
    union { unsigned int u; float f; } x; x.f = f;
    unsigned int r = x.u + 0x7fff + ((x.u >> 16) & 1);
    return (u16)(r >> 16);
}
// fast ELU: t>0 ? t : exp2(t*log2e)-1  (v_exp_f32 path)
__device__ __forceinline__ float elu_fast(float t) {
    return t > 0.f ? t : (__builtin_amdgcn_exp2f(t * 1.44269504088896f) - 1.f);
}
// pack 2 f32 -> 2 fp8 (e4m3) in low 16 bits
__device__ __forceinline__ u32 pk_fp8(float a, float b) {
    return __builtin_amdgcn_cvt_pk_fp8_f32(a, b, 0u, false);
}

// K0: weight prep -> bf16 transposed layouts [c][k]; zeroes per-bucket cursors
__global__ void k_wb(const float* __restrict__ we0, const float* __restrict__ we1,
                     const float* __restrict__ wn0, const float* __restrict__ wn1,
                     u16* __restrict__ wcombt, u16* __restrict__ we1t,
                     u16* __restrict__ wn0t, u16* __restrict__ wn1t,
                     int* __restrict__ gcursor) {
    int i = blockIdx.x * 256 + threadIdx.x;
    if (i < 32768) {                       // wcombt
        int c = i >> 7, k = i & 127;
        float v;
        if (c < 128) v = we0[k * 128 + c] + we0[(256 + k) * 128 + c];
        else { int cc = c - 128; v = we0[(128 + k) * 128 + cc] - we0[(256 + k) * 128 + cc]; }
        wcombt[i] = f2bf(v);
    } else if (i < 49152) {                // we1t
        int j = i - 32768; int c = j >> 7, k = j & 127;
        we1t[j] = f2bf(we1[k * 128 + c]);
    } else if (i < 81920) {                // wn0t (k = 0..255)
        int j = i - 49152; int c = j >> 8, k = j & 255;
        wn0t[j] = f2bf(wn0[k * 128 + c]);
    } else if (i < 98304) {                // wn1t
        int j = i - 81920; int c = j >> 7, k = j & 127;
        wn1t[j] = f2bf(wn1[k * 128 + c]);
    } else if (i < 98304 + NB) {           // gcursor = 0
        gcursor[i - 98304] = 0;
    }
}

// K2 v7: MFMA [P|Q] = x @ Wcomb. 128 rows/block, 4 waves; wave owns TWO 16-row tiles
// (rt=2) -> each wcombt B-frag load feeds 2 MFMAs (2x amortization, 32 acc chains).
// Per lane: single global read of its rows' x; derive A-frags (bf16), xb, fp8 x-slots.
// p8 (fp8 quads): p8[n][4i+0,1] = P[2i],P[2i+1] ; p8[n][4i+2,3] = x[2i],x[2i+1]
// qb[n][128] = Q (bf16) ; xb[n][128] = x (bf16)
__global__ __launch_bounds__(256) void k_pq_mfma(const float* __restrict__ x,
                                                 const u16* __restrict__ wcombt,
                                                 u8* __restrict__ p8, u16* __restrict__ qb,
                                                 u16* __restrict__ xb) {
    __shared__ u8  pq[128 * 272];   // fp8 quad tile (256 B/row + pad)  34.8 KB
    __shared__ u16 qt[128 * 136];   // Q tile (bf16)                    34.8 KB
    int r0 = blockIdx.x * 128;
    int tid = threadIdx.x, wid = tid >> 6, lane = tid & 63;
    int arow = lane & 15, kblk = lane >> 4;
    int rbase = wid * 32;

    short8 a[2][4];
#pragma unroll
    for (int rt = 0; rt < 2; rt++) {
        int row_local = rbase + rt * 16 + arow;          // 0..127
        int nrow = r0 + row_local; if (nrow >= NN) nrow = NN - 1;
        const float* xrow = &x[(size_t)nrow * 128];
        // single global read of this lane's x share (4 ks-chunks x 8 floats)
        float4 xf[8];
#pragma unroll
        for (int ks = 0; ks < 4; ks++) {
            xf[2 * ks]     = *(const float4*)&xrow[ks * 32 + kblk * 8];
            xf[2 * ks + 1] = *(const float4*)&xrow[ks * 32 + kblk * 8 + 4];
        }
        const float* xfp = (const float*)xf;
        // A-frags (bf16) + xb store
#pragma unroll
        for (int ks = 0; ks < 4; ks++) {
            short8 r;
#pragma unroll
            for (int j = 0; j < 8; j++) r[j] = (short)f2bf(xfp[ks * 8 + j]);
            a[rt][ks] = r;
            *(short8*)&xb[(size_t)nrow * 128 + ks * 32 + kblk * 8] = r;
        }
        // fp8 x-slots into LDS quad layout
#pragma unroll
        for (int ks = 0; ks < 4; ks++)
#pragma unroll
            for (int m = 0; m < 4; m++) {
                u16 v = (u16)pk_fp8(xfp[ks * 8 + 2 * m], xfp[ks * 8 + 2 * m + 1]);
                *(u16*)&pq[row_local * 272 + 4 * (ks * 16 + kblk * 4 + m) + 2] = v;
            }
    }

    // ---- MFMA: 16 col-tiles x 4 k-steps x 2 row-tiles (B-frag shared across rt) ----
    floatx4 acc[2][16];
#pragma unroll
    for (int rt = 0; rt < 2; rt++)
#pragma unroll
        for (int n0 = 0; n0 < 16; n0++) acc[rt][n0] = (floatx4)(0.f);
#pragma unroll
    for (int ks = 0; ks < 4; ks++)
#pragma unroll
        for (int n0 = 0; n0 < 16; n0++) {
            short8 b = *(const short8*)&wcombt[(size_t)(n0 * 16 + arow) * 128 + ks * 32 + kblk * 8];
            acc[0][n0] = MFMA(a[0][ks], b, acc[0][n0], 0, 0, 0);
            acc[1][n0] = MFMA(a[1][ks], b, acc[1][n0], 0, 0, 0);
        }

    // ---- epilogue into LDS (own wave's rows; n0 split compile-time uniform) ----
#pragma unroll
    for (int rt = 0; rt < 2; rt++)
#pragma unroll
        for (int n0 = 0; n0 < 16; n0++)
#pragma unroll
            for (int j = 0; j < 4; j++) {
                int r = rbase + rt * 16 + kblk * 4 + j;
                int col = n0 * 16 + arow;
                float v = acc[rt][n0][j];
                if (n0 < 8) pq[r * 272 + 4 * (col >> 1) + (col & 1)] = (u8)pk_fp8(v, v);
                else        qt[r * 136 + (col - 128)] = f2bf(v);
            }
    __syncthreads();
    // ---- coalesced flush ----
    for (int s = tid; s < 128 * 16; s += 256) {
        int r = s >> 4, cb = (s & 15) * 16;
        int n = r0 + r;
        if (n < NN) *(short8*)&p8[(size_t)n * 256 + cb] = *(const short8*)&pq[r * 272 + cb];
    }
    for (int s = tid; s < 128 * 16; s += 256) {
        int r = s >> 4, cb = (s & 15) * 8;
        int n = r0 + r;
        if (n < NN) *(short8*)&qb[(size_t)n * 128 + cb] = *(const short8*)&qt[r * 136 + cb];
    }
}

// K3: bucket scatter into FIXED per-bucket regions (ebuf[b*CAP ...]).
// 8192 edges/block, 32/thread. LDS hist -> reserve region span -> write packed u32.
__global__ __launch_bounds__(256) void k_bscat(const int* __restrict__ ei,
                                               int* __restrict__ gcursor, u32* __restrict__ ebuf) {
    __shared__ int lh[NB], lbase[NB], lrank[NB];
    int tid = threadIdx.x;
    int bs = blockIdx.x * 8192;
    for (int t = tid; t < NB; t += 256) { lh[t] = 0; lrank[t] = 0; }
    __syncthreads();
    int srcv[32], dstv[32];
#pragma unroll
    for (int k = 0; k < 8; k++) {
        int e = bs + k * 1024 + tid * 4;
        int4 s4, d4;
        if (e < NE) { s4 = *(const int4*)&ei[e]; d4 = *(const int4*)&ei[NE + e]; }
        else { s4 = make_int4(0, 0, 0, 0); d4 = make_int4(-1, -1, -1, -1); }
        srcv[4 * k + 0] = s4.x; srcv[4 * k + 1] = s4.y; srcv[4 * k + 2] = s4.z; srcv[4 * k + 3] = s4.w;
        dstv[4 * k + 0] = d4.x; dstv[4 * k + 1] = d4.y; dstv[4 * k + 2] = d4.z; dstv[4 * k + 3] = d4.w;
    }
#pragma unroll
    for (int i = 0; i < 32; i++)
        if (dstv[i] >= 0) atomicAdd(&lh[dstv[i] >> 7], 1);
    __syncthreads();
    for (int t = tid; t < NB; t += 256)
        if (lh[t]) lbase[t] = atomicAdd(&gcursor[t], lh[t]);
    __syncthreads();
#pragma unroll
    for (int i = 0; i < 32; i++) {
        int d = dstv[i];
        if (d >= 0) {
            int b = d >> 7;
            int r = atomicAdd(&lrank[b], 1);
            ebuf[(size_t)b * CAP + lbase[b] + r] = (u32)srcv[i] | ((u32)(d & 127) << 16);
        }
    }
}

// K4: per-bucket counting sort -> per-node [obeg,oend) + srcs (block-exclusive region).
// Zero-pads 8 slack entries so k_agg can prefetch unconditionally.
__global__ __launch_bounds__(256) void k_bsort(const u32* __restrict__ ebuf,
                                               const int* __restrict__ gcursor,
                                               int* __restrict__ obeg, int* __restrict__ oend,
                                               int* __restrict__ srcs) {
    __shared__ int hist[128], excl[128], cur[128];
    int bb = blockIdx.x;
    int tid = threadIdx.x;
    int beg = bb * CAP;
    int cnt = gcursor[bb];
    int end = beg + cnt;
    if (tid < 128) hist[tid] = 0;
    __syncthreads();
    for (int s = beg + tid; s < end; s += 256)
        atomicAdd(&hist[(ebuf[s] >> 16) & 127], 1);
    __syncthreads();
    if (tid == 0) {
        int run = 0;
        for (int i = 0; i < 128; i++) { excl[i] = run; run += hist[i]; }
    }
    __syncthreads();
    int nodebase = bb * 128;
    if (tid < 128) {
        cur[tid] = beg + excl[tid];
        int n = nodebase + tid;
        if (n < NN) {
            obeg[n] = beg + excl[tid];
            oend[n] = beg + excl[tid] + hist[tid];
        }
    }
    if (tid == 0) {
#pragma unroll
        for (int k = 0; k < 8; k++) srcs[end + k] = 0;   // pad: safe prefetch targets
    }
    __syncthreads();
    for (int s = beg + tid; s < end; s += 256) {
        u32 pe = ebuf[s];
        int dl = (pe >> 16) & 127;
        int pos = atomicAdd(&cur[dl], 1);
        srcs[pos] = (int)(pe & 0xFFFF);
    }
}

// K5: one wave per node; fp8 gathers (4 B/lane = 256 B/edge), 32-bit saddr offsets.
// Unmasked full 8-batches + one masked tail batch; unconditional (padded) index prefetch.
//   esumx[n][0:128]   = esum/max(cnt,1)
//   esumx[n][128:256] = (xsum - cnt*x[n])/max(cnt,1)
__global__ __launch_bounds__(256) void k_agg(const u8* __restrict__ p8, const u16* __restrict__ qb,
                                             const u16* __restrict__ xb,
                                             const int* __restrict__ obeg, const int* __restrict__ oend,
                                             const int* __restrict__ srcs,
                                             u16* __restrict__ esumx) {
    const u32* p8r = (const u32*)p8;     // row = 64 dwords; table 12.8 MB -> 32-bit offsets ok
    int wave = threadIdx.x >> 6, lane = threadIdx.x & 63;
    int n = blockIdx.x * 4 + wave;
    if (n >= NN) return;
    int beg = obeg[n], end = oend[n];
    ushort2 qv = *(const ushort2*)(qb + (size_t)n * 128 + 2 * lane);
    float q0 = bf2f(qv.x), q1 = bf2f(qv.y);
    float e0 = 0.f, e1 = 0.f, s0 = 0.f, s1 = 0.f;
    int s = beg;
    if (end > beg) {
        int sr[8];
#pragma unroll
        for (int j = 0; j < 8; j++) sr[j] = srcs[beg + j];         // padded-safe
        for (; s + 8 <= end; s += 8) {
            u32 d[8];
#pragma unroll
            for (int j = 0; j < 8; j++) d[j] = p8r[((u32)sr[j] << 6) + (u32)lane];
            int nb = s + 8;
            if (nb < end) {
#pragma unroll
                for (int j = 0; j < 8; j++) sr[j] = srcs[nb + j];  // padded-safe
            }
#pragma unroll
            for (int j = 0; j < 8; j++) {
                f32x2 pp = __builtin_amdgcn_cvt_pk_f32_fp8(d[j], false);
                f32x2 xp = __builtin_amdgcn_cvt_pk_f32_fp8(d[j], true);
                e0 += elu_fast(pp[0] + q0);
                e1 += elu_fast(pp[1] + q1);
                s0 += xp[0]; s1 += xp[1];
            }
        }
        if (s < end) {   // masked tail batch; pad indices gather node 0 (valid), masked out
            u32 d[8];
#pragma unroll
            for (int j = 0; j < 8; j++) d[j] = p8r[((u32)sr[j] << 6) + (u32)lane];
#pragma unroll
            for (int j = 0; j < 8; j++) {
                bool live = (s + j < end);  // wave-uniform
                f32x2 pp = __builtin_amdgcn_cvt_pk_f32_fp8(d[j], false);
                f32x2 xp = __builtin_amdgcn_cvt_pk_f32_fp8(d[j], true);
                float c0 = elu_fast(pp[0] + q0), c1 = elu_fast(pp[1] + q1);
                e0 += live ? c0 : 0.f;
                e1 += live ? c1 : 0.f;
                s0 += live ? xp[0] : 0.f;
                s1 += live ? xp[1] : 0.f;
            }
        }
    }
    float cntf = (float)(end - beg);
    float inv = 1.f / fmaxf(cntf, 1.f);
    ushort2 xo = *(const ushort2*)(xb + (size_t)n * 128 + 2 * lane);  // own x (bf16)
    s0 = (s0 - cntf * bf2f(xo.x)) * inv;
    s1 = (s1 - cntf * bf2f(xo.y)) * inv;
    e0 *= inv; e1 *= inv;
    ushort2 oe = { f2bf(e0), f2bf(e1) };
    ushort2 os = { f2bf(s0), f2bf(s1) };
    *(ushort2*)(esumx + (size_t)n * 256 + 2 * lane) = oe;
    *(ushort2*)(esumx + (size_t)n * 256 + 128 + 2 * lane) = os;
}

// K6: MFMA node MLP. 128 rows/block, 4 waves; wave owns rows end-to-end, no barriers,
// all global inputs prefetched at entry.
__global__ __launch_bounds__(256, 2) void k_node_mfma(const float* __restrict__ x,
                                                      const u16* __restrict__ xb,
                                                      const u16* __restrict__ esumx,
                                                      const u16* __restrict__ we1t,
                                                      const u16* __restrict__ wn0t,
                                                      const u16* __restrict__ wn1t,
                                                      float* __restrict__ out) {
    __shared__ u16 tile[128 * 136];
    int r0 = blockIdx.x * 128;
    int tid = threadIdx.x, wid = tid >> 6, lane = tid & 63;
    int arow = lane & 15, kblk = lane >> 4;
    int rbase = wid * 32;
    int nrow[2];
#pragma unroll
    for (int rt = 0; rt < 2; rt++) {
        int n = r0 + rbase + rt * 16 + arow; if (n >= NN) n = NN - 1;
        nrow[rt] = n;
    }
    short8 stg[8];
#pragma unroll
    for (int t = 0; t < 8; t++) {
        int idx = t * 64 + lane;
        int r = idx >> 4, cb = (idx & 15) * 8;
        int n = r0 + rbase + r; if (n >= NN) n = NN - 1;
        stg[t] = *(const short8*)&esumx[(size_t)n * 256 + 128 + cb];
    }
    short8 a1[2][4], ax[2][4];
#pragma unroll
    for (int rt = 0; rt < 2; rt++)
#pragma unroll
        for (int ks = 0; ks < 4; ks++) {
            a1[rt][ks] = *(const short8*)&esumx[(size_t)nrow[rt] * 256 + ks * 32 + kblk * 8];
            ax[rt][ks] = *(const short8*)&xb[(size_t)nrow[rt] * 128 + ks * 32 + kblk * 8];
        }
#pragma unroll
    for (int t = 0; t < 8; t++) {
        int idx = t * 64 + lane;
        int r = rbase + (idx >> 4), cb = (idx & 15) * 8;
        *(short8*)&tile[r * 136 + cb] = stg[t];
    }
    floatx4 acc[2][8];
#pragma unroll
    for (int rt = 0; rt < 2; rt++)
#pragma unroll
        for (int n0 = 0; n0 < 8; n0++) acc[rt][n0] = (floatx4)(0.f);
#pragma unroll
    for (int ks = 0; ks < 4; ks++)
#pragma unroll
        for (int n0 = 0; n0 < 8; n0++) {
            short8 b = *(const short8*)&we1t[(size_t)(n0 * 16 + arow) * 128 + ks * 32 + kblk * 8];
            acc[0][n0] = MFMA(a1[0][ks], b, acc[0][n0], 0, 0, 0);
            acc[1][n0] = MFMA(a1[1][ks], b, acc[1][n0], 0, 0, 0);
        }
#pragma unroll
    for (int rt = 0; rt < 2; rt++)
#pragma unroll
        for (int n0 = 0; n0 < 8; n0++)
#pragma unroll
            for (int j = 0; j < 4; j++) {
                int rloc = rbase + rt * 16 + kblk * 4 + j;
                int col = n0 * 16 + arow;
                float m = acc[rt][n0][j] + bf2f(tile[rloc * 136 + col]);
                tile[rloc * 136 + col] = f2bf(m);
            }
#pragma unroll
    for (int rt = 0; rt < 2; rt++)
#pragma unroll
        for (int n0 = 0; n0 < 8; n0++) acc[rt][n0] = (floatx4)(0.f);
#pragma unroll
    for (int ks = 0; ks < 4; ks++) {
        short8 am[2];
#pragma unroll
        for (int rt = 0; rt < 2; rt++)
            am[rt] = *(const short8*)&tile[(rbase + rt * 16 + arow) * 136 + ks * 32 + kblk * 8];
#pragma unroll
        for (int n0 = 0; n0 < 8; n0++) {
            short8 bx = *(const short8*)&wn0t[(size_t)(n0 * 16 + arow) * 256 + ks * 32 + kblk * 8];
            short8 bm = *(const short8*)&wn0t[(size_t)(n0 * 16 + arow) * 256 + 128 + ks * 32 + kblk * 8];
#pragma unroll
            for (int rt = 0; rt < 2; rt++) {
                acc[rt][n0] = MFMA(ax[rt][ks], bx, acc[rt][n0], 0, 0, 0);
                acc[rt][n0] = MFMA(am[rt], bm, acc[rt][n0], 0, 0, 0);
            }
        }
    }
#pragma unroll
    for (int rt = 0; rt < 2; rt++)
#pragma unroll
        for (int n0 = 0; n0 < 8; n0++)
#pragma unroll
            for (int j = 0; j < 4; j++) {
                int rloc = rbase + rt * 16 + kblk * 4 + j;
                tile[rloc * 136 + n0 * 16 + arow] = f2bf(elu_fast(acc[rt][n0][j]));
            }
#pragma unroll
    for (int rt = 0; rt < 2; rt++)
#pragma unroll
        for (int n0 = 0; n0 < 8; n0++) acc[rt][n0] = (floatx4)(0.f);
#pragma unroll
    for (int ks = 0; ks < 4; ks++) {
        short8 a[2];
#pragma unroll
        for (int rt = 0; rt < 2; rt++)
            a[rt] = *(const short8*)&tile[(rbase + rt * 16 + arow) * 136 + ks * 32 + kblk * 8];
#pragma unroll
        for (int n0 = 0; n0 < 8; n0++) {
            short8 b = *(const short8*)&wn1t[(size_t)(n0 * 16 + arow) * 128 + ks * 32 + kblk * 8];
            acc[0][n0] = MFMA(a[0], b, acc[0][n0], 0, 0, 0);
            acc[1][n0] = MFMA(a[1], b, acc[1][n0], 0, 0, 0);
        }
    }
#pragma unroll
    for (int rt = 0; rt < 2; rt++)
#pragma unroll
        for (int n0 = 0; n0 < 8; n0++)
#pragma unroll
            for (int j = 0; j < 4; j++)
                tile[(rbase + rt * 16 + kblk * 4 + j) * 136 + n0 * 16 + arow] = f2bf(acc[rt][n0][j]);
#pragma unroll
    for (int t = 0; t < 16; t++) {
        int idx = t * 64 + lane;
        int r = idx >> 5, cb = (idx & 31) * 4;
        int n = r0 + rbase + r;
        if (n < NN) {
            float4 xv = *(const float4*)&x[(size_t)n * 128 + cb];
            ushort4 tv = *(const ushort4*)&tile[(rbase + r) * 136 + cb];
            float4 o = { xv.x + bf2f(tv.x), xv.y + bf2f(tv.y), xv.z + bf2f(tv.z), xv.w + bf2f(tv.w) };
            *(float4*)&out[(size_t)n * 128 + cb] = o;
        }
    }
}

extern "C" void kernel_launch(void* const* d_in, const int* in_sizes, int n_in,
                              void* d_out, int out_size, void* d_ws, size_t ws_size,
                              hipStream_t stream) {
    const float* x       = (const float*)d_in[0];
    const int* ei        = (const int*)d_in[1];   // int64 in reference -> int32 from harness
    const float* we0     = (const float*)d_in[2];
    const float* we1     = (const float*)d_in[3];
    const float* wn0     = (const float*)d_in[4];
    const float* wn1     = (const float*)d_in[5];
    float* out           = (float*)d_out;

    char* w = (char*)d_ws;
    size_t off = 0;
    auto alloc = [&](size_t bytes) -> void* {
        off = (off + 255) & ~(size_t)255;
        void* p = w + off;
        off += bytes;
        return p;
    };
    u16*   wcombt = (u16*)alloc(256 * 128 * sizeof(u16));
    u16*   we1t   = (u16*)alloc(128 * 128 * sizeof(u16));
    u16*   wn0t   = (u16*)alloc(128 * 256 * sizeof(u16));
    u16*   wn1t   = (u16*)alloc(128 * 128 * sizeof(u16));
    u8*    p8     = (u8*)alloc((size_t)NN * 256 * sizeof(u8));
    u16*   qb     = (u16*)alloc((size_t)NN * 128 * sizeof(u16));
    u16*   xb     = (u16*)alloc((size_t)NN * 128 * sizeof(u16));
    u16*   esumx  = (u16*)alloc((size_t)NN * 256 * sizeof(u16));
    int*   gcursor= (int*)alloc(NB * sizeof(int));
    u32*   ebuf   = (u32*)alloc((size_t)NB * CAP * sizeof(u32));
    int*   obeg   = (int*)alloc((size_t)NN * sizeof(int));
    int*   oend   = (int*)alloc((size_t)NN * sizeof(int));
    int*   srcs   = (int*)alloc(((size_t)NB * CAP + 64) * sizeof(int));
    (void)ws_size; (void)in_sizes; (void)n_in; (void)out_size;  // ~78 MB of d_ws used

    k_wb<<<(98304 + NB + 255) / 256, 256, 0, stream>>>(we0, we1, wn0, wn1,
                                                       wcombt, we1t, wn0t, wn1t, gcursor);
    k_pq_mfma<<<(NN + 127) / 128, 256, 0, stream>>>(x, wcombt, p8, qb, xb);
    k_bscat<<<(NE + 8191) / 8192, 256, 0, stream>>>(ei, gcursor, ebuf);
    k_bsort<<<NB, 256, 0, stream>>>(ebuf, gcursor, obeg, oend, srcs);
    k_agg<<<(NN + 3) / 4, 256, 0, stream>>>(p8, qb, xb, obeg, oend, srcs, esumx);
    k_node_mfma<<<(NN + 127) / 128, 256, 0, stream>>>(x, xb, esumx, we1t, wn0t, wn1t, out);
}

// Round 14
// 141.858 us; speedup vs baseline: 10.5154x; 1.0755x over previous
//
#include <hip/hip_runtime.h>
#include <hip/hip_bf16.h>

// Problem constants (from reference)
#define NN 50000
#define NE 800000
#define HD 128
#define NB 391              // buckets of 128 dst nodes: (NN+127)>>7
#define CAP 4096            // fixed bucket capacity: mean 2048, sigma ~45 -> +45 sigma
#define PQ_BLOCKS 391      // (NN+127)/128
#define SCAT_BLOCKS ((NE + 8191) / 8192)

typedef unsigned short u16;
typedef unsigned char u8;
typedef unsigned int u32;
typedef __attribute__((ext_vector_type(8))) short short8;
typedef __attribute__((ext_vector_type(4))) float floatx4;
typedef __attribute__((ext_vector_type(2))) float f32x2;
#define MFMA __builtin_amdgcn_mfma_f32_16x16x32_bf16

__device__ __forceinline__ float bf2f(u16 v) {
    union { unsigned int u; float f; } x; x.u = ((unsigned int)v) << 16; return x.f;
}
__device__ __forceinline__ u16 f2bf(float f) {
    union { unsigned int u; float f; } x; x.f = f;
    unsigned int r = x.u + 0x7fff + ((x.u >> 16) & 1);
    return (u16)(r >> 16);
}
// fast ELU: t>0 ? t : exp2(t*log2e)-1  (v_exp_f32 path)
__device__ __forceinline__ float elu_fast(float t) {
    return t > 0.f ? t : (__builtin_amdgcn_exp2f(t * 1.44269504088896f) - 1.f);
}
// pack 2 f32 -> 2 fp8 (e4m3) in low 16 bits
__device__ __forceinline__ u32 pk_fp8(float a, float b) {
    return __builtin_amdgcn_cvt_pk_fp8_f32(a, b, 0u, false);
}

// K0: weight prep -> bf16 transposed layouts [c][k]; zeroes per-bucket cursors
__global__ void k_wb(const float* __restrict__ we0, const float* __restrict__ we1,
                     const float* __restrict__ wn0, const float* __restrict__ wn1,
                     u16* __restrict__ wcombt, u16* __restrict__ we1t,
                     u16* __restrict__ wn0t, u16* __restrict__ wn1t,
                     int* __restrict__ gcursor) {
    int i = blockIdx.x * 256 + threadIdx.x;
    if (i < 32768) {                       // wcombt
        int c = i >> 7, k = i & 127;
        float v;
        if (c < 128) v = we0[k * 128 + c] + we0[(256 + k) * 128 + c];
        else { int cc = c - 128; v = we0[(128 + k) * 128 + cc] - we0[(256 + k) * 128 + cc]; }
        wcombt[i] = f2bf(v);
    } else if (i < 49152) {                // we1t
        int j = i - 32768; int c = j >> 7, k = j & 127;
        we1t[j] = f2bf(we1[k * 128 + c]);
    } else if (i < 81920) {                // wn0t (k = 0..255)
        int j = i - 49152; int c = j >> 8, k = j & 255;
        wn0t[j] = f2bf(wn0[k * 128 + c]);
    } else if (i < 98304) {                // wn1t
        int j = i - 81920; int c = j >> 7, k = j & 127;
        wn1t[j] = f2bf(wn1[k * 128 + c]);
    } else if (i < 98304 + NB) {           // gcursor = 0
        gcursor[i - 98304] = 0;
    }
}

// K1 (fused): blocks [0, PQ_BLOCKS) = PQ MFMA; blocks [PQ_BLOCKS, +SCAT_BLOCKS) = bucket
// scatter. The two halves have disjoint inputs (x/wcombt vs ei) and outputs
// (p8/qb/xb vs ebuf/gcursor) -> safe to co-schedule; bscat's memory work overlaps
// the latency-bound PQ half.
__global__ __launch_bounds__(256) void k_front(const float* __restrict__ x,
                                               const u16* __restrict__ wcombt,
                                               u8* __restrict__ p8, u16* __restrict__ qb,
                                               u16* __restrict__ xb,
                                               const int* __restrict__ ei,
                                               int* __restrict__ gcursor, u32* __restrict__ ebuf) {
    int tid = threadIdx.x;
    if (blockIdx.x < PQ_BLOCKS) {
        // ======== PQ half: [P|Q] = x @ Wcomb, 128 rows/block, rt=2 per wave ========
        __shared__ u8  pq[128 * 272];
        __shared__ u16 qt[128 * 136];
        int r0 = blockIdx.x * 128;
        int wid = tid >> 6, lane = tid & 63;
        int arow = lane & 15, kblk = lane >> 4;
        int rbase = wid * 32;

        short8 a[2][4];
#pragma unroll
        for (int rt = 0; rt < 2; rt++) {
            int row_local = rbase + rt * 16 + arow;
            int nrow = r0 + row_local; if (nrow >= NN) nrow = NN - 1;
            const float* xrow = &x[(size_t)nrow * 128];
            float4 xf[8];
#pragma unroll
            for (int ks = 0; ks < 4; ks++) {
                xf[2 * ks]     = *(const float4*)&xrow[ks * 32 + kblk * 8];
                xf[2 * ks + 1] = *(const float4*)&xrow[ks * 32 + kblk * 8 + 4];
            }
            const float* xfp = (const float*)xf;
#pragma unroll
            for (int ks = 0; ks < 4; ks++) {
                short8 r;
#pragma unroll
                for (int j = 0; j < 8; j++) r[j] = (short)f2bf(xfp[ks * 8 + j]);
                a[rt][ks] = r;
                *(short8*)&xb[(size_t)nrow * 128 + ks * 32 + kblk * 8] = r;
            }
#pragma unroll
            for (int ks = 0; ks < 4; ks++)
#pragma unroll
                for (int m = 0; m < 4; m++) {
                    u16 v = (u16)pk_fp8(xfp[ks * 8 + 2 * m], xfp[ks * 8 + 2 * m + 1]);
                    *(u16*)&pq[row_local * 272 + 4 * (ks * 16 + kblk * 4 + m) + 2] = v;
                }
        }
        floatx4 acc[2][16];
#pragma unroll
        for (int rt = 0; rt < 2; rt++)
#pragma unroll
            for (int n0 = 0; n0 < 16; n0++) acc[rt][n0] = (floatx4)(0.f);
#pragma unroll
        for (int ks = 0; ks < 4; ks++)
#pragma unroll
            for (int n0 = 0; n0 < 16; n0++) {
                short8 b = *(const short8*)&wcombt[(size_t)(n0 * 16 + arow) * 128 + ks * 32 + kblk * 8];
                acc[0][n0] = MFMA(a[0][ks], b, acc[0][n0], 0, 0, 0);
                acc[1][n0] = MFMA(a[1][ks], b, acc[1][n0], 0, 0, 0);
            }
#pragma unroll
        for (int rt = 0; rt < 2; rt++)
#pragma unroll
            for (int n0 = 0; n0 < 16; n0++)
#pragma unroll
                for (int j = 0; j < 4; j++) {
                    int r = rbase + rt * 16 + kblk * 4 + j;
                    int col = n0 * 16 + arow;
                    float v = acc[rt][n0][j];
                    if (n0 < 8) pq[r * 272 + 4 * (col >> 1) + (col & 1)] = (u8)pk_fp8(v, v);
                    else        qt[r * 136 + (col - 128)] = f2bf(v);
                }
        __syncthreads();
        for (int s = tid; s < 128 * 16; s += 256) {
            int r = s >> 4, cb = (s & 15) * 16;
            int n = r0 + r;
            if (n < NN) *(short8*)&p8[(size_t)n * 256 + cb] = *(const short8*)&pq[r * 272 + cb];
        }
        for (int s = tid; s < 128 * 16; s += 256) {
            int r = s >> 4, cb = (s & 15) * 8;
            int n = r0 + r;
            if (n < NN) *(short8*)&qb[(size_t)n * 128 + cb] = *(const short8*)&qt[r * 136 + cb];
        }
    } else {
        // ======== bscat half: bucket scatter into fixed regions ========
        __shared__ int lh[NB], lbase[NB], lrank[NB];
        int bs = (blockIdx.x - PQ_BLOCKS) * 8192;
        for (int t = tid; t < NB; t += 256) { lh[t] = 0; lrank[t] = 0; }
        __syncthreads();
        int srcv[32], dstv[32];
#pragma unroll
        for (int k = 0; k < 8; k++) {
            int e = bs + k * 1024 + tid * 4;
            int4 s4, d4;
            if (e < NE) { s4 = *(const int4*)&ei[e]; d4 = *(const int4*)&ei[NE + e]; }
            else { s4 = make_int4(0, 0, 0, 0); d4 = make_int4(-1, -1, -1, -1); }
            srcv[4 * k + 0] = s4.x; srcv[4 * k + 1] = s4.y; srcv[4 * k + 2] = s4.z; srcv[4 * k + 3] = s4.w;
            dstv[4 * k + 0] = d4.x; dstv[4 * k + 1] = d4.y; dstv[4 * k + 2] = d4.z; dstv[4 * k + 3] = d4.w;
        }
#pragma unroll
        for (int i = 0; i < 32; i++)
            if (dstv[i] >= 0) atomicAdd(&lh[dstv[i] >> 7], 1);
        __syncthreads();
        for (int t = tid; t < NB; t += 256)
            if (lh[t]) lbase[t] = atomicAdd(&gcursor[t], lh[t]);
        __syncthreads();
#pragma unroll
        for (int i = 0; i < 32; i++) {
            int d = dstv[i];
            if (d >= 0) {
                int b = d >> 7;
                int r = atomicAdd(&lrank[b], 1);
                ebuf[(size_t)b * CAP + lbase[b] + r] = (u32)srcv[i] | ((u32)(d & 127) << 16);
            }
        }
    }
}

// K4: per-bucket counting sort -> per-node [obeg,oend) + srcs (block-exclusive region).
// Zero-pads 8 slack entries so k_agg can prefetch unconditionally.
__global__ __launch_bounds__(256) void k_bsort(const u32* __restrict__ ebuf,
                                               const int* __restrict__ gcursor,
                                               int* __restrict__ obeg, int* __restrict__ oend,
                                               int* __restrict__ srcs) {
    __shared__ int hist[128], excl[128], cur[128];
    int bb = blockIdx.x;
    int tid = threadIdx.x;
    int beg = bb * CAP;
    int cnt = gcursor[bb];
    int end = beg + cnt;
    if (tid < 128) hist[tid] = 0;
    __syncthreads();
    for (int s = beg + tid; s < end; s += 256)
        atomicAdd(&hist[(ebuf[s] >> 16) & 127], 1);
    __syncthreads();
    if (tid == 0) {
        int run = 0;
        for (int i = 0; i < 128; i++) { excl[i] = run; run += hist[i]; }
    }
    __syncthreads();
    int nodebase = bb * 128;
    if (tid < 128) {
        cur[tid] = beg + excl[tid];
        int n = nodebase + tid;
        if (n < NN) {
            obeg[n] = beg + excl[tid];
            oend[n] = beg + excl[tid] + hist[tid];
        }
    }
    if (tid == 0) {
#pragma unroll
        for (int k = 0; k < 8; k++) srcs[end + k] = 0;   // pad: safe prefetch targets
    }
    __syncthreads();
    for (int s = beg + tid; s < end; s += 256) {
        u32 pe = ebuf[s];
        int dl = (pe >> 16) & 127;
        int pos = atomicAdd(&cur[dl], 1);
        srcs[pos] = (int)(pe & 0xFFFF);
    }
}

// K5: one wave per node; fp8 gathers (4 B/lane = 256 B/edge), 32-bit saddr offsets.
// Unmasked full 8-batches + one masked tail batch; unconditional (padded) index prefetch.
//   esumx[n][0:128]   = esum/max(cnt,1)
//   esumx[n][128:256] = (xsum - cnt*x[n])/max(cnt,1)
__global__ __launch_bounds__(256) void k_agg(const u8* __restrict__ p8, const u16* __restrict__ qb,
                                             const u16* __restrict__ xb,
                                             const int* __restrict__ obeg, const int* __restrict__ oend,
                                             const int* __restrict__ srcs,
                                             u16* __restrict__ esumx) {
    const u32* p8r = (const u32*)p8;     // row = 64 dwords; table 12.8 MB -> 32-bit offsets ok
    int wave = threadIdx.x >> 6, lane = threadIdx.x & 63;
    int n = blockIdx.x * 4 + wave;
    if (n >= NN) return;
    int beg = obeg[n], end = oend[n];
    ushort2 qv = *(const ushort2*)(qb + (size_t)n * 128 + 2 * lane);
    float q0 = bf2f(qv.x), q1 = bf2f(qv.y);
    float e0 = 0.f, e1 = 0.f, s0 = 0.f, s1 = 0.f;
    int s = beg;
    if (end > beg) {
        int sr[8];
#pragma unroll
        for (int j = 0; j < 8; j++) sr[j] = srcs[beg + j];         // padded-safe
        for (; s + 8 <= end; s += 8) {
            u32 d[8];
#pragma unroll
            for (int j = 0; j < 8; j++) d[j] = p8r[((u32)sr[j] << 6) + (u32)lane];
            int nb = s + 8;
            if (nb < end) {
#pragma unroll
                for (int j = 0; j < 8; j++) sr[j] = srcs[nb + j];  // padded-safe
            }
#pragma unroll
            for (int j = 0; j < 8; j++) {
                f32x2 pp = __builtin_amdgcn_cvt_pk_f32_fp8(d[j], false);
                f32x2 xp = __builtin_amdgcn_cvt_pk_f32_fp8(d[j], true);
                e0 += elu_fast(pp[0] + q0);
                e1 += elu_fast(pp[1] + q1);
                s0 += xp[0]; s1 += xp[1];
            }
        }
        if (s < end) {   // masked tail batch; pad indices gather node 0 (valid), masked out
            u32 d[8];
#pragma unroll
            for (int j = 0; j < 8; j++) d[j] = p8r[((u32)sr[j] << 6) + (u32)lane];
#pragma unroll
            for (int j = 0; j < 8; j++) {
                bool live = (s + j < end);  // wave-uniform
                f32x2 pp = __builtin_amdgcn_cvt_pk_f32_fp8(d[j], false);
                f32x2 xp = __builtin_amdgcn_cvt_pk_f32_fp8(d[j], true);
                float c0 = elu_fast(pp[0] + q0), c1 = elu_fast(pp[1] + q1);
                e0 += live ? c0 : 0.f;
                e1 += live ? c1 : 0.f;
                s0 += live ? xp[0] : 0.f;
                s1 += live ? xp[1] : 0.f;
            }
        }
    }
    float cntf = (float)(end - beg);
    float inv = 1.f / fmaxf(cntf, 1.f);
    ushort2 xo = *(const ushort2*)(xb + (size_t)n * 128 + 2 * lane);  // own x (bf16)
    s0 = (s0 - cntf * bf2f(xo.x)) * inv;
    s1 = (s1 - cntf * bf2f(xo.y)) * inv;
    e0 *= inv; e1 *= inv;
    ushort2 oe = { f2bf(e0), f2bf(e1) };
    ushort2 os = { f2bf(s0), f2bf(s1) };
    *(ushort2*)(esumx + (size_t)n * 256 + 2 * lane) = oe;
    *(ushort2*)(esumx + (size_t)n * 256 + 128 + 2 * lane) = os;
}

// K6: MFMA node MLP. 128 rows/block, 4 waves; wave owns rows end-to-end, no barriers,
// all global inputs prefetched at entry.
__global__ __launch_bounds__(256, 2) void k_node_mfma(const float* __restrict__ x,
                                                      const u16* __restrict__ xb,
                                                      const u16* __restrict__ esumx,
                                                      const u16* __restrict__ we1t,
                                                      const u16* __restrict__ wn0t,
                                                      const u16* __restrict__ wn1t,
                                                      float* __restrict__ out) {
    __shared__ u16 tile[128 * 136];
    int r0 = blockIdx.x * 128;
    int tid = threadIdx.x, wid = tid >> 6, lane = tid & 63;
    int arow = lane & 15, kblk = lane >> 4;
    int rbase = wid * 32;
    int nrow[2];
#pragma unroll
    for (int rt = 0; rt < 2; rt++) {
        int n = r0 + rbase + rt * 16 + arow; if (n >= NN) n = NN - 1;
        nrow[rt] = n;
    }
    short8 stg[8];
#pragma unroll
    for (int t = 0; t < 8; t++) {
        int idx = t * 64 + lane;
        int r = idx >> 4, cb = (idx & 15) * 8;
        int n = r0 + rbase + r; if (n >= NN) n = NN - 1;
        stg[t] = *(const short8*)&esumx[(size_t)n * 256 + 128 + cb];
    }
    short8 a1[2][4], ax[2][4];
#pragma unroll
    for (int rt = 0; rt < 2; rt++)
#pragma unroll
        for (int ks = 0; ks < 4; ks++) {
            a1[rt][ks] = *(const short8*)&esumx[(size_t)nrow[rt] * 256 + ks * 32 + kblk * 8];
            ax[rt][ks] = *(const short8*)&xb[(size_t)nrow[rt] * 128 + ks * 32 + kblk * 8];
        }
#pragma unroll
    for (int t = 0; t < 8; t++) {
        int idx = t * 64 + lane;
        int r = rbase + (idx >> 4), cb = (idx & 15) * 8;
        *(short8*)&tile[r * 136 + cb] = stg[t];
    }
    floatx4 acc[2][8];
#pragma unroll
    for (int rt = 0; rt < 2; rt++)
#pragma unroll
        for (int n0 = 0; n0 < 8; n0++) acc[rt][n0] = (floatx4)(0.f);
#pragma unroll
    for (int ks = 0; ks < 4; ks++)
#pragma unroll
        for (int n0 = 0; n0 < 8; n0++) {
            short8 b = *(const short8*)&we1t[(size_t)(n0 * 16 + arow) * 128 + ks * 32 + kblk * 8];
            acc[0][n0] = MFMA(a1[0][ks], b, acc[0][n0], 0, 0, 0);
            acc[1][n0] = MFMA(a1[1][ks], b, acc[1][n0], 0, 0, 0);
        }
#pragma unroll
    for (int rt = 0; rt < 2; rt++)
#pragma unroll
        for (int n0 = 0; n0 < 8; n0++)
#pragma unroll
            for (int j = 0; j < 4; j++) {
                int rloc = rbase + rt * 16 + kblk * 4 + j;
                int col = n0 * 16 + arow;
                float m = acc[rt][n0][j] + bf2f(tile[rloc * 136 + col]);
                tile[rloc * 136 + col] = f2bf(m);
            }
#pragma unroll
    for (int rt = 0; rt < 2; rt++)
#pragma unroll
        for (int n0 = 0; n0 < 8; n0++) acc[rt][n0] = (floatx4)(0.f);
#pragma unroll
    for (int ks = 0; ks < 4; ks++) {
        short8 am[2];
#pragma unroll
        for (int rt = 0; rt < 2; rt++)
            am[rt] = *(const short8*)&tile[(rbase + rt * 16 + arow) * 136 + ks * 32 + kblk * 8];
#pragma unroll
        for (int n0 = 0; n0 < 8; n0++) {
            short8 bx = *(const short8*)&wn0t[(size_t)(n0 * 16 + arow) * 256 + ks * 32 + kblk * 8];
            short8 bm = *(const short8*)&wn0t[(size_t)(n0 * 16 + arow) * 256 + 128 + ks * 32 + kblk * 8];
#pragma unroll
            for (int rt = 0; rt < 2; rt++) {
                acc[rt][n0] = MFMA(ax[rt][ks], bx, acc[rt][n0], 0, 0, 0);
                acc[rt][n0] = MFMA(am[rt], bm, acc[rt][n0], 0, 0, 0);
            }
        }
    }
#pragma unroll
    for (int rt = 0; rt < 2; rt++)
#pragma unroll
        for (int n0 = 0; n0 < 8; n0++)
#pragma unroll
            for (int j = 0; j < 4; j++) {
                int rloc = rbase + rt * 16 + kblk * 4 + j;
                tile[rloc * 136 + n0 * 16 + arow] = f2bf(elu_fast(acc[rt][n0][j]));
            }
#pragma unroll
    for (int rt = 0; rt < 2; rt++)
#pragma unroll
        for (int n0 = 0; n0 < 8; n0++) acc[rt][n0] = (floatx4)(0.f);
#pragma unroll
    for (int ks = 0; ks < 4; ks++) {
        short8 a[2];
#pragma unroll
        for (int rt = 0; rt < 2; rt++)
            a[rt] = *(const short8*)&tile[(rbase + rt * 16 + arow) * 136 + ks * 32 + kblk * 8];
#pragma unroll
        for (int n0 = 0; n0 < 8; n0++) {
            short8 b = *(const short8*)&wn1t[(size_t)(n0 * 16 + arow) * 128 + ks * 32 + kblk * 8];
            acc[0][n0] = MFMA(a[0], b, acc[0][n0], 0, 0, 0);
            acc[1][n0] = MFMA(a[1], b, acc[1][n0], 0, 0, 0);
        }
    }
#pragma unroll
    for (int rt = 0; rt < 2; rt++)
#pragma unroll
        for (int n0 = 0; n0 < 8; n0++)
#pragma unroll
            for (int j = 0; j < 4; j++)
                tile[(rbase + rt * 16 + kblk * 4 + j) * 136 + n0 * 16 + arow] = f2bf(acc[rt][n0][j]);
#pragma unroll
    for (int t = 0; t < 16; t++) {
        int idx = t * 64 + lane;
        int r = idx >> 5, cb = (idx & 31) * 4;
        int n = r0 + rbase + r;
        if (n < NN) {
            float4 xv = *(const float4*)&x[(size_t)n * 128 + cb];
            ushort4 tv = *(const ushort4*)&tile[(rbase + r) * 136 + cb];
            float4 o = { xv.x + bf2f(tv.x), xv.y + bf2f(tv.y), xv.z + bf2f(tv.z), xv.w + bf2f(tv.w) };
            *(float4*)&out[(size_t)n * 128 + cb] = o;
        }
    }
}

extern "C" void kernel_launch(void* const* d_in, const int* in_sizes, int n_in,
                              void* d_out, int out_size, void* d_ws, size_t ws_size,
                              hipStream_t stream) {
    const float* x       = (const float*)d_in[0];
    const int* ei        = (const int*)d_in[1];   // int64 in reference -> int32 from harness
    const float* we0     = (const float*)d_in[2];
    const float* we1     = (const float*)d_in[3];
    const float* wn0     = (const float*)d_in[4];
    const float* wn1     = (const float*)d_in[5];
    float* out           = (float*)d_out;

    char* w = (char*)d_ws;
    size_t off = 0;
    auto alloc = [&](size_t bytes) -> void* {
        off = (off + 255) & ~(size_t)255;
        void* p = w + off;
        off += bytes;
        return p;
    };
    u16*   wcombt = (u16*)alloc(256 * 128 * sizeof(u16));
    u16*   we1t   = (u16*)alloc(128 * 128 * sizeof(u16));
    u16*   wn0t   = (u16*)alloc(128 * 256 * sizeof(u16));
    u16*   wn1t   = (u16*)alloc(128 * 128 * sizeof(u16));
    u8*    p8     = (u8*)alloc((size_t)NN * 256 * sizeof(u8));
    u16*   qb     = (u16*)alloc((size_t)NN * 128 * sizeof(u16));
    u16*   xb     = (u16*)alloc((size_t)NN * 128 * sizeof(u16));
    u16*   esumx  = (u16*)alloc((size_t)NN * 256 * sizeof(u16));
    int*   gcursor= (int*)alloc(NB * sizeof(int));
    u32*   ebuf   = (u32*)alloc((size_t)NB * CAP * sizeof(u32));
    int*   obeg   = (int*)alloc((size_t)NN * sizeof(int));
    int*   oend   = (int*)alloc((size_t)NN * sizeof(int));
    int*   srcs   = (int*)alloc(((size_t)NB * CAP + 64) * sizeof(int));
    (void)ws_size; (void)in_sizes; (void)n_in; (void)out_size;  // ~78 MB of d_ws used

    k_wb<<<(98304 + NB + 255) / 256, 256, 0, stream>>>(we0, we1, wn0, wn1,
                                                       wcombt, we1t, wn0t, wn1t, gcursor);
    k_front<<<PQ_BLOCKS + SCAT_BLOCKS, 256, 0, stream>>>(x, wcombt, p8, qb, xb,
                                                         ei, gcursor, ebuf);
    k_bsort<<<NB, 256, 0, stream>>>(ebuf, gcursor, obeg, oend, srcs);
    k_agg<<<(NN + 3) / 4, 256, 0, stream>>>(p8, qb, xb, obeg, oend, srcs, esumx);
    k_node_mfma<<<(NN + 127) / 128, 256, 0, stream>>>(x, xb, esumx, we1t, wn0t, wn1t, out);
}